// Round 4
// baseline (319.847 us; speedup 1.0000x reference)
//
#include <hip/hip_runtime.h>
#include <hip/hip_bf16.h>
#include <math.h>
#include <stdint.h>

#define B_ 8
#define T_ 2048
#define E_ 512
#define CCH 256
#define NC_ 8
#define EPS_ 1e-3f
#define QSCALE 0.044194173824159216f   // 512^-0.5

typedef __attribute__((ext_vector_type(8))) short short8;
typedef __attribute__((ext_vector_type(4))) float f32x4;
typedef __hip_bfloat16 bf16_t;

__device__ __forceinline__ short f2bs(float x) {
    bf16_t h = __float2bfloat16(x);
    return __builtin_bit_cast(short, h);
}

// async global->LDS, 16B per lane; LDS dest is wave-uniform base + lane*16
__device__ __forceinline__ void async16(const void* g, void* l) {
    __builtin_amdgcn_global_load_lds(
        (const __attribute__((address_space(1))) unsigned int*)(unsigned long long)(uintptr_t)g,
        (__attribute__((address_space(3))) unsigned int*)(unsigned int)(uintptr_t)l,
        16, 0, 0);
}

// ---------------------------------------------------------------------------
// Shared GEMM core: C[128x128] += A[128xK] * (B^T[128xK])^T, bf16 in, fp32 acc.
// Operands row-major, K contiguous. 256 threads = 4 waves 2x2; each wave 64x64
// = 4x4 MFMA 16x16x32 tiles. BK=64.
// LDS layout: per 1KB window (8 rows): [chunk(8)][row(8)][16B].  Lane l of a
// staging instr fetches global (row = l&7, kchunk = l>>3) -> fragment reads are
// 8-lane-consecutive 16B chunks covering all 32 banks (2-way alias = free).
// ---------------------------------------------------------------------------
__device__ __forceinline__ void gemm128(const short* __restrict__ Ag, int lda,
                                        const short* __restrict__ Bg, int ldb, int K,
                                        short* Al, short* Bl, f32x4 acc[4][4],
                                        int wm, int wn, int wq, int lane) {
    int m16 = lane & 15, quad = lane >> 4;
    int r8 = lane & 7, c8 = (lane >> 3) * 8;
    for (int k0 = 0; k0 < K; k0 += 64) {
        __syncthreads();
        #pragma unroll
        for (int w = 0; w < 4; ++w) {
            int R = wq * 32 + w * 8;
            async16(Ag + (size_t)(R + r8) * lda + k0 + c8, Al + R * 64);
            async16(Bg + (size_t)(R + r8) * ldb + k0 + c8, Bl + R * 64);
        }
        __syncthreads();
        #pragma unroll
        for (int h = 0; h < 2; ++h) {
            int co = (h * 4 + quad) * 64 + (m16 >> 3) * 512 + (m16 & 7) * 8;
            short8 a[4], b[4];
            #pragma unroll
            for (int i = 0; i < 4; ++i)
                a[i] = *(const short8*)(Al + (wm + i * 16) * 64 + co);
            #pragma unroll
            for (int i = 0; i < 4; ++i)
                b[i] = *(const short8*)(Bl + (wn + i * 16) * 64 + co);
            #pragma unroll
            for (int i = 0; i < 4; ++i)
                #pragma unroll
                for (int j = 0; j < 4; ++j)
                    acc[i][j] = __builtin_amdgcn_mfma_f32_16x16x32_bf16(a[i], b[j], acc[i][j], 0, 0, 0);
        }
    }
}

#define GEMM_PROLOG \
    int tid = threadIdx.x, lane = tid & 63, wq = tid >> 6; \
    int wm = (wq & 1) * 64, wn = (wq >> 1) * 64; \
    int m16 = lane & 15, quad = lane >> 4; \
    (void)tid; \
    f32x4 acc[4][4]; \
    { f32x4 zz = {0.f, 0.f, 0.f, 0.f}; \
      for (int i = 0; i < 4; ++i) for (int j = 0; j < 4; ++j) acc[i][j] = zz; }

// ---------------------------------------------------------------------------
__global__ void castw_kernel(const float* __restrict__ qw, const float* __restrict__ kw,
                             const float* __restrict__ vw, const float* __restrict__ ow,
                             short* __restrict__ wbf) {
    size_t idx8 = ((size_t)blockIdx.x * 256 + threadIdx.x) * 8;
    int sel = (int)(idx8 >> 18);
    size_t off = idx8 & ((1u << 18) - 1);
    const float* src = sel == 0 ? qw : sel == 1 ? kw : sel == 2 ? vw : ow;
    const float4* sp = (const float4*)(src + off);
    float4 a = sp[0], b = sp[1];
    short8 g;
    g[0] = f2bs(a.x); g[1] = f2bs(a.y); g[2] = f2bs(a.z); g[3] = f2bs(a.w);
    g[4] = f2bs(b.x); g[5] = f2bs(b.y); g[6] = f2bs(b.z); g[7] = f2bs(b.w);
    *(short8*)(wbf + idx8) = g;
}

// ---------------------------------------------------------------------------
__global__ void transpose_x_kernel(const float* __restrict__ x, short* __restrict__ xbf) {
    __shared__ __align__(16) float S[64][68];
    int tid = threadIdx.x;
    int t0 = blockIdx.x * 64, e0 = blockIdx.y * 64, b = blockIdx.z;
    const float* src = x + ((size_t)b * E_ + e0) * T_ + t0;
    short* dst = xbf + ((size_t)b * T_ + t0) * E_ + e0;
    #pragma unroll
    for (int p = 0; p < 2; ++p) {
        int el = p * 32 + (tid >> 3), tc = (tid & 7) * 8;
        const float4* sp = (const float4*)(src + (size_t)el * T_ + tc);
        *(float4*)&S[el][tc] = sp[0];
        *(float4*)&S[el][tc + 4] = sp[1];
    }
    __syncthreads();
    #pragma unroll
    for (int p = 0; p < 2; ++p) {
        int tl = p * 32 + (tid >> 3), ec = (tid & 7) * 8;
        short8 g;
        #pragma unroll
        for (int j = 0; j < 8; ++j) g[j] = f2bs(S[ec + j][tl]);
        *(short8*)(dst + (size_t)tl * E_ + ec) = g;
    }
}

// ---------------------------------------------------------------------------
__global__ void transpose_bf_kernel(const short* __restrict__ k, const short* __restrict__ v,
                                    short* __restrict__ kT, short* __restrict__ vT) {
    __shared__ __align__(16) short S[64][72];
    int tid = threadIdx.x;
    int t0 = blockIdx.x * 64, e0 = blockIdx.y * 64;
    int b = blockIdx.z >> 1, which = blockIdx.z & 1;
    const short* src = (which ? v : k) + ((size_t)b * T_ + t0) * E_ + e0;
    short* dst = (which ? vT : kT) + ((size_t)b * E_ + e0) * T_ + t0;
    #pragma unroll
    for (int p = 0; p < 2; ++p) {
        int tl = p * 32 + (tid >> 3), ec = (tid & 7) * 8;
        *(short8*)&S[tl][ec] = *(const short8*)(src + (size_t)tl * E_ + ec);
    }
    __syncthreads();
    #pragma unroll
    for (int p = 0; p < 2; ++p) {
        int er = p * 32 + (tid >> 3), tc = (tid & 7) * 8;
        short8 g;
        #pragma unroll
        for (int j = 0; j < 8; ++j) g[j] = S[tc + j][er];
        *(short8*)(dst + (size_t)er * T_ + tc) = g;
    }
}

// ---------------------------------------------------------------------------
__global__ __launch_bounds__(256) void proj_qkv_kernel(
    const short* __restrict__ xbf, const short* __restrict__ wbf,
    const float* __restrict__ qb, const float* __restrict__ kb, const float* __restrict__ vb,
    const float* __restrict__ toep,
    bf16_t* __restrict__ qraw, bf16_t* __restrict__ kout, bf16_t* __restrict__ vout) {
    __shared__ __align__(16) short Al[128 * 64], Bl[128 * 64];
    GEMM_PROLOG
    int t0 = blockIdx.x * 128, i0 = blockIdx.y * 128;
    int b = blockIdx.z / 3, sel = blockIdx.z % 3;
    const short* Ag = xbf + ((size_t)b * T_ + t0) * E_;
    const short* Bg = wbf + (size_t)sel * E_ * E_ + (size_t)i0 * E_;
    gemm128(Ag, E_, Bg, E_, E_, Al, Bl, acc, wm, wn, wq, lane);
    const float* bias = (sel == 0) ? qb : (sel == 1) ? kb : vb;
    #pragma unroll
    for (int mt = 0; mt < 4; ++mt)
        #pragma unroll
        for (int r = 0; r < 4; ++r) {
            int t = t0 + wm + mt * 16 + quad * 4 + r;
            size_t rowoff = ((size_t)b * T_ + t) * E_;
            float tw = toep[t];
            #pragma unroll
            for (int nt = 0; nt < 4; ++nt) {
                int col = i0 + wn + nt * 16 + m16;
                float vv = acc[mt][nt][r] + bias[col];
                if (sel == 0) qraw[rowoff + col] = __float2bfloat16(vv);
                else if (sel == 1) kout[rowoff + col] = __float2bfloat16(expf(vv));
                else vout[rowoff + col] = __float2bfloat16(vv * tw);
            }
        }
}

// ---------------------------------------------------------------------------
__global__ void softmax_kernel(const bf16_t* __restrict__ qraw, bf16_t* __restrict__ qbf) {
    __shared__ float red[256];
    int row = blockIdx.x, tid = threadIdx.x;
    const bf16_t* p = qraw + (size_t)row * E_;
    float v0 = __bfloat162float(p[tid]), v1 = __bfloat162float(p[tid + 256]);
    red[tid] = fmaxf(v0, v1);
    __syncthreads();
    for (int s = 128; s > 0; s >>= 1) { if (tid < s) red[tid] = fmaxf(red[tid], red[tid + s]); __syncthreads(); }
    float m = red[0];
    __syncthreads();
    float e0 = expf(v0 - m), e1 = expf(v1 - m);
    red[tid] = e0 + e1;
    __syncthreads();
    for (int s = 128; s > 0; s >>= 1) { if (tid < s) red[tid] += red[tid + s]; __syncthreads(); }
    float inv = QSCALE / red[0];
    qbf[(size_t)row * E_ + tid] = __float2bfloat16(e0 * inv);
    qbf[(size_t)row * E_ + tid + 256] = __float2bfloat16(e1 * inv);
}

// ---------------------------------------------------------------------------
__global__ __launch_bounds__(256) void chunk_kv_kernel(
    const short* __restrict__ vT, const short* __restrict__ kT, bf16_t* __restrict__ KV) {
    __shared__ __align__(16) short Al[128 * 64], Bl[128 * 64];
    GEMM_PROLOG
    int ev0 = blockIdx.x * 128, ek0 = blockIdx.y * 128;
    int bc = blockIdx.z, b = bc >> 3, c = bc & 7;
    const short* Ag = vT + ((size_t)b * E_ + ev0) * T_ + c * CCH;
    const short* Bg = kT + ((size_t)b * E_ + ek0) * T_ + c * CCH;
    gemm128(Ag, T_, Bg, T_, CCH, Al, Bl, acc, wm, wn, wq, lane);
    #pragma unroll
    for (int mt = 0; mt < 4; ++mt)
        #pragma unroll
        for (int r = 0; r < 4; ++r) {
            int ev = ev0 + wm + mt * 16 + quad * 4 + r;
            #pragma unroll
            for (int nt = 0; nt < 4; ++nt) {
                int ek = ek0 + wn + nt * 16 + m16;
                KV[((size_t)bc * E_ + ev) * E_ + ek] = __float2bfloat16(acc[mt][nt][r]);
            }
        }
}

// ---------------------------------------------------------------------------
__global__ void scan_kv_kernel(bf16_t* __restrict__ KV) {
    size_t gid = (size_t)blockIdx.x * 256 + threadIdx.x;
    size_t b = gid >> 18, idx = gid & ((1u << 18) - 1);
    bf16_t* p = KV + b * ((size_t)NC_ * E_ * E_) + idx;
    float run = 0.f;
    for (int c = 0; c < NC_; ++c) {
        float t = __bfloat162float(*p);
        *p = __float2bfloat16(run);
        run += t;
        p += (size_t)E_ * E_;
    }
}

// ---------------------------------------------------------------------------
__global__ void ksum_kernel(const bf16_t* __restrict__ k, float* __restrict__ ks) {
    int bc = blockIdx.x, b = bc >> 3, c = bc & 7;
    int e = blockIdx.y * 256 + threadIdx.x;
    const bf16_t* kp = k + ((size_t)b * T_ + (size_t)c * CCH) * E_ + e;
    float s = 0.f;
    for (int t = 0; t < CCH; ++t) s += __bfloat162float(kp[(size_t)t * E_]);
    ks[(size_t)bc * E_ + e] = s;
}
__global__ void scan_f_kernel(float* __restrict__ buf, int nper) {
    int gid = blockIdx.x * 256 + threadIdx.x;
    int b = gid / nper, idx = gid % nper;
    float run = 0.f;
    float* p = buf + (size_t)b * NC_ * nper + idx;
    for (int c = 0; c < NC_; ++c) { float t = *p; *p = run; run += t; p += nper; }
}

// ---------------------------------------------------------------------------
__global__ __launch_bounds__(256) void pmat_kernel(
    const short* __restrict__ qbf, const short* __restrict__ kbf, bf16_t* __restrict__ P) {
    __shared__ __align__(16) short Al[128 * 64], Bl[128 * 64];
    int tj0 = blockIdx.x * 128, ti0 = blockIdx.y * 128;
    int bc = blockIdx.z, b = bc >> 3, c = bc & 7;
    short* Pp = (short*)P + (size_t)bc * CCH * CCH;
    if (tj0 > ti0) {           // fully above diagonal: zero-fill (ws is poisoned)
        short8 z8 = {0, 0, 0, 0, 0, 0, 0, 0};
        for (int i = threadIdx.x; i < 128 * 128 / 8; i += 256) {
            int row = i >> 4, colc = (i * 8) & 127;
            *(short8*)(Pp + (size_t)(ti0 + row) * CCH + tj0 + colc) = z8;
        }
        return;
    }
    GEMM_PROLOG
    const short* Ag = qbf + ((size_t)b * T_ + c * CCH + ti0) * E_;
    const short* Bg = kbf + ((size_t)b * T_ + c * CCH + tj0) * E_;
    gemm128(Ag, E_, Bg, E_, E_, Al, Bl, acc, wm, wn, wq, lane);
    #pragma unroll
    for (int mt = 0; mt < 4; ++mt)
        #pragma unroll
        for (int r = 0; r < 4; ++r) {
            int row = ti0 + wm + mt * 16 + quad * 4 + r;
            #pragma unroll
            for (int nt = 0; nt < 4; ++nt) {
                int col = tj0 + wn + nt * 16 + m16;
                float vv = (col <= row) ? acc[mt][nt][r] : 0.f;
                ((bf16_t*)Pp)[(size_t)row * CCH + col] = __float2bfloat16(vv);
            }
        }
}

// ---------------------------------------------------------------------------
__global__ void denom_kernel(const bf16_t* __restrict__ qbf, const float* __restrict__ z,
                             const bf16_t* __restrict__ P, float* __restrict__ invd) {
    __shared__ float red[256];
    int row = blockIdx.x, tid = threadIdx.x;
    int b = row >> 11, t = row & (T_ - 1);
    int c = t >> 8, tl = t & 255;
    const bf16_t* qr = qbf + (size_t)row * E_;
    const float* zr = z + ((size_t)(b * NC_ + c)) * E_;
    const bf16_t* Pr = P + (((size_t)(b * NC_ + c)) * CCH + tl) * CCH;
    float s = __bfloat162float(qr[tid]) * zr[tid]
            + __bfloat162float(qr[tid + 256]) * zr[tid + 256]
            + __bfloat162float(Pr[tid]);
    red[tid] = s;
    __syncthreads();
    for (int st = 128; st > 0; st >>= 1) { if (tid < st) red[tid] += red[tid + st]; __syncthreads(); }
    if (tid == 0) invd[row] = 1.f / fmaxf(red[0], EPS_);
}

// ---------------------------------------------------------------------------
__global__ __launch_bounds__(256) void attnout_kernel(
    const short* __restrict__ qbf, const short* __restrict__ KV,
    const short* __restrict__ P, const short* __restrict__ vT,
    const float* __restrict__ invd, bf16_t* __restrict__ attn) {
    __shared__ __align__(16) short Al[128 * 64], Bl[128 * 64];
    GEMM_PROLOG
    int t0 = blockIdx.x * 128, i0 = blockIdx.y * 128, b = blockIdx.z;
    int c = t0 >> 8, tl0 = t0 & 255, bc = b * NC_ + c;
    gemm128(qbf + ((size_t)b * T_ + t0) * E_, E_,
            KV + ((size_t)bc * E_ + i0) * E_, E_, E_, Al, Bl, acc, wm, wn, wq, lane);
    gemm128(P + ((size_t)bc * CCH + tl0) * CCH, CCH,
            vT + ((size_t)b * E_ + i0) * T_ + c * CCH, T_, CCH, Al, Bl, acc, wm, wn, wq, lane);
    #pragma unroll
    for (int mt = 0; mt < 4; ++mt)
        #pragma unroll
        for (int r = 0; r < 4; ++r) {
            int t = t0 + wm + mt * 16 + quad * 4 + r;
            float sc = invd[(size_t)b * T_ + t];
            #pragma unroll
            for (int nt = 0; nt < 4; ++nt) {
                int col = i0 + wn + nt * 16 + m16;
                attn[((size_t)b * T_ + t) * E_ + col] = __float2bfloat16(acc[mt][nt][r] * sc);
            }
        }
}

// ---------------------------------------------------------------------------
__global__ __launch_bounds__(256) void outproj_kernel(
    const short* __restrict__ attn, const short* __restrict__ wbf_o,
    const float* __restrict__ ob, float* __restrict__ out) {
    __shared__ __align__(16) short Al[128 * 64], Bl[128 * 64];
    GEMM_PROLOG
    int t0 = blockIdx.x * 128, i0 = blockIdx.y * 128, b = blockIdx.z;
    gemm128(attn + ((size_t)b * T_ + t0) * E_, E_,
            wbf_o + (size_t)i0 * E_, E_, E_, Al, Bl, acc, wm, wn, wq, lane);
    #pragma unroll
    for (int mt = 0; mt < 4; ++mt)
        #pragma unroll
        for (int r = 0; r < 4; ++r) {
            int t = t0 + wm + mt * 16 + quad * 4 + r;
            #pragma unroll
            for (int nt = 0; nt < 4; ++nt) {
                int col = i0 + wn + nt * 16 + m16;
                out[((size_t)b * T_ + t) * E_ + col] = acc[mt][nt][r] + ob[col];
            }
        }
}

// ---------------------------------------------------------------------------
extern "C" void kernel_launch(void* const* d_in, const int* in_sizes, int n_in,
                              void* d_out, int out_size, void* d_ws, size_t ws_size,
                              hipStream_t stream) {
    const float* x    = (const float*)d_in[0];
    const float* toep = (const float*)d_in[1];
    const float* q_w  = (const float*)d_in[2];
    const float* q_b  = (const float*)d_in[3];
    const float* k_w  = (const float*)d_in[4];
    const float* k_b  = (const float*)d_in[5];
    const float* v_w  = (const float*)d_in[6];
    const float* v_b  = (const float*)d_in[7];
    const float* o_w  = (const float*)d_in[8];
    const float* o_b  = (const float*)d_in[9];

    const size_t NTE = (size_t)B_ * T_ * E_;          // 8388608
    char* base = (char*)d_ws;
    short* xbf  = (short*)base;  base += NTE * 2;
    short* wbf  = (short*)base;  base += (size_t)4 * E_ * E_ * 2;
    short* qraw = (short*)base;  base += NTE * 2;
    short* qbf  = (short*)base;  base += NTE * 2;
    short* kbf  = (short*)base;  base += NTE * 2;
    short* vbf  = (short*)base;  base += NTE * 2;
    short* kT   = (short*)base;  base += NTE * 2;
    short* vT   = (short*)base;  base += NTE * 2;
    short* KV   = (short*)base;  base += (size_t)B_ * NC_ * E_ * E_ * 2;
    short* P    = (short*)base;  base += (size_t)B_ * NC_ * CCH * CCH * 2;
    float* ksum = (float*)base;  base += (size_t)B_ * NC_ * E_ * 4;
    float* invd = (float*)base;  base += (size_t)B_ * T_ * 4;
    short* attn = xbf;           // xbf dead after proj_qkv: reuse for attn bf16
    float* out  = (float*)d_out;

    dim3 blk(256);
    castw_kernel<<<dim3(512), blk, 0, stream>>>(q_w, k_w, v_w, o_w, wbf);
    transpose_x_kernel<<<dim3(32, 8, 8), blk, 0, stream>>>(x, xbf);
    proj_qkv_kernel<<<dim3(16, 4, 24), blk, 0, stream>>>(
        xbf, wbf, q_b, k_b, v_b, toep, (bf16_t*)qraw, (bf16_t*)kbf, (bf16_t*)vbf);
    softmax_kernel<<<dim3(B_ * T_), blk, 0, stream>>>((const bf16_t*)qraw, (bf16_t*)qbf);
    transpose_bf_kernel<<<dim3(32, 8, 16), blk, 0, stream>>>(kbf, vbf, kT, vT);
    chunk_kv_kernel<<<dim3(4, 4, 64), blk, 0, stream>>>(vT, kT, (bf16_t*)KV);
    scan_kv_kernel<<<dim3(8192), blk, 0, stream>>>((bf16_t*)KV);
    ksum_kernel<<<dim3(64, 2), blk, 0, stream>>>((const bf16_t*)kbf, ksum);
    scan_f_kernel<<<dim3(16), blk, 0, stream>>>(ksum, E_);
    pmat_kernel<<<dim3(2, 2, 64), blk, 0, stream>>>(qbf, kbf, (bf16_t*)P);
    denom_kernel<<<dim3(B_ * T_), blk, 0, stream>>>(
        (const bf16_t*)qbf, ksum, (const bf16_t*)P, invd);
    attnout_kernel<<<dim3(16, 4, 8), blk, 0, stream>>>(
        qbf, KV, P, vT, invd, (bf16_t*)attn);
    outproj_kernel<<<dim3(16, 4, 8), blk, 0, stream>>>(
        attn, wbf + (size_t)3 * E_ * E_, o_b, out);
}

// Round 5
// 310.928 us; speedup vs baseline: 1.0287x; 1.0287x over previous
//
#include <hip/hip_runtime.h>
#include <hip/hip_bf16.h>
#include <math.h>
#include <stdint.h>

#define B_ 8
#define T_ 2048
#define E_ 512
#define CCH 256
#define NC_ 8
#define EPS_ 1e-3f
#define QSCALE 0.044194173824159216f   // 512^-0.5

typedef __attribute__((ext_vector_type(8))) short short8;
typedef __attribute__((ext_vector_type(4))) float f32x4;
typedef __hip_bfloat16 bf16_t;

__device__ __forceinline__ short f2bs(float x) {
    bf16_t h = __float2bfloat16(x);
    return __builtin_bit_cast(short, h);
}

// async global->LDS, 16B per lane; LDS dest is wave-uniform base + lane*16
__device__ __forceinline__ void async16(const void* g, void* l) {
    __builtin_amdgcn_global_load_lds(
        (const __attribute__((address_space(1))) unsigned int*)(unsigned long long)(uintptr_t)g,
        (__attribute__((address_space(3))) unsigned int*)(unsigned int)(uintptr_t)l,
        16, 0, 0);
}

// ---------------------------------------------------------------------------
// Shared GEMM core: C[128x128] += A[128xK] * (B^T[128xK])^T, bf16 in, fp32 acc.
// Operands row-major, K contiguous. 256 threads = 4 waves 2x2; each wave 64x64
// = 4x4 MFMA 16x16x32 tiles. BK=32, 16 KB LDS (6 blocks/CU).
// LDS: 8 windows of 1KB (16 rows each): [kchunk(4)][row(16)][16B].
//   DMA lane l -> global(row=16w+(l&15), kcol=(l>>4)*8), LDS w*1KB + l*16B.
//   Fragment read (row m, kchunk=quad): (m&~15)*32 + quad*128 + (m&15)*8 shorts
//   -> 16 consecutive 16B chunks per (i,quad): 2-way bank alias = free.
// ---------------------------------------------------------------------------
__device__ __forceinline__ void gemm128(const short* __restrict__ Ag, int lda,
                                        const short* __restrict__ Bg, int ldb, int K,
                                        short* Al, short* Bl, f32x4 acc[4][4],
                                        int wm, int wn, int wq, int lane) {
    int m16 = lane & 15, quad = lane >> 4;
    int r16 = lane & 15, c4 = (lane >> 4) * 8;
    for (int k0 = 0; k0 < K; k0 += 32) {
        __syncthreads();
        #pragma unroll
        for (int w = 0; w < 2; ++w) {
            int win = wq + w * 4;
            int R = win * 16;
            async16(Ag + (size_t)(R + r16) * lda + k0 + c4, Al + win * 512);
            async16(Bg + (size_t)(R + r16) * ldb + k0 + c4, Bl + win * 512);
        }
        __syncthreads();
        short8 a[4], b[4];
        #pragma unroll
        for (int i = 0; i < 4; ++i)
            a[i] = *(const short8*)(Al + (wm + i * 16) * 32 + quad * 128 + m16 * 8);
        #pragma unroll
        for (int i = 0; i < 4; ++i)
            b[i] = *(const short8*)(Bl + (wn + i * 16) * 32 + quad * 128 + m16 * 8);
        #pragma unroll
        for (int i = 0; i < 4; ++i)
            #pragma unroll
            for (int j = 0; j < 4; ++j)
                acc[i][j] = __builtin_amdgcn_mfma_f32_16x16x32_bf16(a[i], b[j], acc[i][j], 0, 0, 0);
    }
}

#define GEMM_PROLOG \
    int tid = threadIdx.x, lane = tid & 63, wq = tid >> 6; \
    int wm = (wq & 1) * 64, wn = (wq >> 1) * 64; \
    int m16 = lane & 15, quad = lane >> 4; \
    (void)tid; \
    f32x4 acc[4][4]; \
    { f32x4 zz = {0.f, 0.f, 0.f, 0.f}; \
      for (int i = 0; i < 4; ++i) for (int j = 0; j < 4; ++j) acc[i][j] = zz; }

// ---------------------------------------------------------------------------
// prep: blocks [0,512) cast weights fp32->bf16; blocks [512,2560) transpose x.
// ---------------------------------------------------------------------------
__global__ void prep_kernel(const float* __restrict__ qw, const float* __restrict__ kw,
                            const float* __restrict__ vw, const float* __restrict__ ow,
                            short* __restrict__ wbf,
                            const float* __restrict__ x, short* __restrict__ xbf) {
    int bid = blockIdx.x;
    int tid = threadIdx.x;
    if (bid < 512) {
        size_t idx8 = ((size_t)bid * 256 + tid) * 8;
        int sel = (int)(idx8 >> 18);
        size_t off = idx8 & ((1u << 18) - 1);
        const float* src = sel == 0 ? qw : sel == 1 ? kw : sel == 2 ? vw : ow;
        const float4* sp = (const float4*)(src + off);
        float4 a = sp[0], b = sp[1];
        short8 g;
        g[0] = f2bs(a.x); g[1] = f2bs(a.y); g[2] = f2bs(a.z); g[3] = f2bs(a.w);
        g[4] = f2bs(b.x); g[5] = f2bs(b.y); g[6] = f2bs(b.z); g[7] = f2bs(b.w);
        *(short8*)(wbf + idx8) = g;
        return;
    }
    bid -= 512;
    __shared__ __align__(16) float S[64][68];
    int t0 = (bid & 31) * 64, e0 = ((bid >> 5) & 7) * 64, b = bid >> 8;
    const float* src = x + ((size_t)b * E_ + e0) * T_ + t0;
    short* dst = xbf + ((size_t)b * T_ + t0) * E_ + e0;
    #pragma unroll
    for (int p = 0; p < 2; ++p) {
        int el = p * 32 + (tid >> 3), tc = (tid & 7) * 8;
        const float4* sp = (const float4*)(src + (size_t)el * T_ + tc);
        *(float4*)&S[el][tc] = sp[0];
        *(float4*)&S[el][tc + 4] = sp[1];
    }
    __syncthreads();
    #pragma unroll
    for (int p = 0; p < 2; ++p) {
        int tl = p * 32 + (tid >> 3), ec = (tid & 7) * 8;
        short8 g;
        #pragma unroll
        for (int j = 0; j < 8; ++j) g[j] = f2bs(S[ec + j][tl]);
        *(short8*)(dst + (size_t)tl * E_ + ec) = g;
    }
}

// ---------------------------------------------------------------------------
__global__ void transpose_bf_kernel(const short* __restrict__ k, const short* __restrict__ v,
                                    short* __restrict__ kT, short* __restrict__ vT) {
    __shared__ __align__(16) short S[64][72];
    int tid = threadIdx.x;
    int t0 = blockIdx.x * 64, e0 = blockIdx.y * 64;
    int b = blockIdx.z >> 1, which = blockIdx.z & 1;
    const short* src = (which ? v : k) + ((size_t)b * T_ + t0) * E_ + e0;
    short* dst = (which ? vT : kT) + ((size_t)b * E_ + e0) * T_ + t0;
    #pragma unroll
    for (int p = 0; p < 2; ++p) {
        int tl = p * 32 + (tid >> 3), ec = (tid & 7) * 8;
        *(short8*)&S[tl][ec] = *(const short8*)(src + (size_t)tl * E_ + ec);
    }
    __syncthreads();
    #pragma unroll
    for (int p = 0; p < 2; ++p) {
        int er = p * 32 + (tid >> 3), tc = (tid & 7) * 8;
        short8 g;
        #pragma unroll
        for (int j = 0; j < 8; ++j) g[j] = S[tc + j][er];
        *(short8*)(dst + (size_t)er * T_ + tc) = g;
    }
}

// ---------------------------------------------------------------------------
__global__ __launch_bounds__(256) void proj_qkv_kernel(
    const short* __restrict__ xbf, const short* __restrict__ wbf,
    const float* __restrict__ qb, const float* __restrict__ kb, const float* __restrict__ vb,
    const float* __restrict__ toep,
    bf16_t* __restrict__ qraw, bf16_t* __restrict__ kout, bf16_t* __restrict__ vout) {
    __shared__ __align__(16) short Al[128 * 32], Bl[128 * 32];
    GEMM_PROLOG
    int t0 = blockIdx.x * 128, i0 = blockIdx.y * 128;
    int b = blockIdx.z / 3, sel = blockIdx.z % 3;
    const short* Ag = xbf + ((size_t)b * T_ + t0) * E_;
    const short* Bg = wbf + (size_t)sel * E_ * E_ + (size_t)i0 * E_;
    gemm128(Ag, E_, Bg, E_, E_, Al, Bl, acc, wm, wn, wq, lane);
    const float* bias = (sel == 0) ? qb : (sel == 1) ? kb : vb;
    #pragma unroll
    for (int mt = 0; mt < 4; ++mt)
        #pragma unroll
        for (int r = 0; r < 4; ++r) {
            int t = t0 + wm + mt * 16 + quad * 4 + r;
            size_t rowoff = ((size_t)b * T_ + t) * E_;
            float tw = toep[t];
            #pragma unroll
            for (int nt = 0; nt < 4; ++nt) {
                int col = i0 + wn + nt * 16 + m16;
                float vv = acc[mt][nt][r] + bias[col];
                if (sel == 0) qraw[rowoff + col] = __float2bfloat16(vv);
                else if (sel == 1) kout[rowoff + col] = __float2bfloat16(expf(vv));
                else vout[rowoff + col] = __float2bfloat16(vv * tw);
            }
        }
}

// ---------------------------------------------------------------------------
// blocks [0,16384): softmax over q rows; blocks [16384,16512): per-chunk ksum
// ---------------------------------------------------------------------------
__global__ void softmax_ksum_kernel(const bf16_t* __restrict__ qraw, bf16_t* __restrict__ qbf,
                                    const bf16_t* __restrict__ k, float* __restrict__ ks) {
    int bid = blockIdx.x, tid = threadIdx.x;
    if (bid >= B_ * T_) {
        int r = bid - B_ * T_;             // 128 blocks: (bc=64, half=2)
        int bc = r >> 1, b = bc >> 3, c = bc & 7;
        int e = (r & 1) * 256 + tid;
        const bf16_t* kp = k + ((size_t)b * T_ + (size_t)c * CCH) * E_ + e;
        float s = 0.f;
        for (int t = 0; t < CCH; ++t) s += __bfloat162float(kp[(size_t)t * E_]);
        ks[(size_t)bc * E_ + e] = s;
        return;
    }
    __shared__ float red[256];
    const bf16_t* p = qraw + (size_t)bid * E_;
    float v0 = __bfloat162float(p[tid]), v1 = __bfloat162float(p[tid + 256]);
    red[tid] = fmaxf(v0, v1);
    __syncthreads();
    for (int s = 128; s > 0; s >>= 1) { if (tid < s) red[tid] = fmaxf(red[tid], red[tid + s]); __syncthreads(); }
    float m = red[0];
    __syncthreads();
    float e0 = expf(v0 - m), e1 = expf(v1 - m);
    red[tid] = e0 + e1;
    __syncthreads();
    for (int s = 128; s > 0; s >>= 1) { if (tid < s) red[tid] += red[tid + s]; __syncthreads(); }
    float inv = QSCALE / red[0];
    qbf[(size_t)bid * E_ + tid] = __float2bfloat16(e0 * inv);
    qbf[(size_t)bid * E_ + tid + 256] = __float2bfloat16(e1 * inv);
}

// ---------------------------------------------------------------------------
// blocks [0,1024): chunk KV^T; blocks [1024,1280): intra-chunk P matrix
// ---------------------------------------------------------------------------
__global__ __launch_bounds__(256) void kvp_kernel(
    const short* __restrict__ vT, const short* __restrict__ kT, bf16_t* __restrict__ KV,
    const short* __restrict__ qbf, const short* __restrict__ kbf, bf16_t* __restrict__ P) {
    __shared__ __align__(16) short Al[128 * 32], Bl[128 * 32];
    int bid = blockIdx.x;
    if (bid < 1024) {
        GEMM_PROLOG
        int ev0 = (bid & 3) * 128, ek0 = ((bid >> 2) & 3) * 128;
        int bc = bid >> 4, b = bc >> 3, c = bc & 7;
        const short* Ag = vT + ((size_t)b * E_ + ev0) * T_ + c * CCH;
        const short* Bg = kT + ((size_t)b * E_ + ek0) * T_ + c * CCH;
        gemm128(Ag, T_, Bg, T_, CCH, Al, Bl, acc, wm, wn, wq, lane);
        #pragma unroll
        for (int mt = 0; mt < 4; ++mt)
            #pragma unroll
            for (int r = 0; r < 4; ++r) {
                int ev = ev0 + wm + mt * 16 + quad * 4 + r;
                #pragma unroll
                for (int nt = 0; nt < 4; ++nt) {
                    int ek = ek0 + wn + nt * 16 + m16;
                    KV[((size_t)bc * E_ + ev) * E_ + ek] = __float2bfloat16(acc[mt][nt][r]);
                }
            }
        return;
    }
    bid -= 1024;
    int tj0 = (bid & 1) * 128, ti0 = ((bid >> 1) & 1) * 128;
    int bc = bid >> 2, b = bc >> 3, c = bc & 7;
    short* Pp = (short*)P + (size_t)bc * CCH * CCH;
    if (tj0 > ti0) {           // above diagonal: zero-fill (ws is poisoned)
        short8 z8 = {0, 0, 0, 0, 0, 0, 0, 0};
        for (int i = threadIdx.x; i < 128 * 128 / 8; i += 256) {
            int row = i >> 4, colc = (i * 8) & 127;
            *(short8*)(Pp + (size_t)(ti0 + row) * CCH + tj0 + colc) = z8;
        }
        return;
    }
    GEMM_PROLOG
    const short* Ag = qbf + ((size_t)b * T_ + c * CCH + ti0) * E_;
    const short* Bg = kbf + ((size_t)b * T_ + c * CCH + tj0) * E_;
    gemm128(Ag, E_, Bg, E_, E_, Al, Bl, acc, wm, wn, wq, lane);
    #pragma unroll
    for (int mt = 0; mt < 4; ++mt)
        #pragma unroll
        for (int r = 0; r < 4; ++r) {
            int row = ti0 + wm + mt * 16 + quad * 4 + r;
            #pragma unroll
            for (int nt = 0; nt < 4; ++nt) {
                int col = tj0 + wn + nt * 16 + m16;
                float vv = (col <= row) ? acc[mt][nt][r] : 0.f;
                ((bf16_t*)Pp)[(size_t)row * CCH + col] = __float2bfloat16(vv);
            }
        }
}

// ---------------------------------------------------------------------------
// blocks [0,8192): exclusive chunk-scan of KV (bf16); [8192,8208): scan ksum
// ---------------------------------------------------------------------------
__global__ void scan2_kernel(bf16_t* __restrict__ KV, float* __restrict__ ks) {
    size_t bid = blockIdx.x;
    if (bid < 8192) {
        size_t gid = bid * 256 + threadIdx.x;
        size_t b = gid >> 18, idx = gid & ((1u << 18) - 1);
        bf16_t* p = KV + b * ((size_t)NC_ * E_ * E_) + idx;
        float run = 0.f;
        for (int c = 0; c < NC_; ++c) {
            float t = __bfloat162float(*p);
            *p = __float2bfloat16(run);
            run += t;
            p += (size_t)E_ * E_;
        }
        return;
    }
    int gid = (int)(bid - 8192) * 256 + threadIdx.x;   // B*E = 4096 ids
    int b = gid >> 9, idx = gid & (E_ - 1);
    float run = 0.f;
    float* p = ks + (size_t)b * NC_ * E_ + idx;
    for (int c = 0; c < NC_; ++c) { float t = *p; *p = run; run += t; p += E_; }
}

// ---------------------------------------------------------------------------
__global__ void denom_kernel(const bf16_t* __restrict__ qbf, const float* __restrict__ z,
                             const bf16_t* __restrict__ P, float* __restrict__ invd) {
    __shared__ float red[256];
    int row = blockIdx.x, tid = threadIdx.x;
    int b = row >> 11, t = row & (T_ - 1);
    int c = t >> 8, tl = t & 255;
    const bf16_t* qr = qbf + (size_t)row * E_;
    const float* zr = z + ((size_t)(b * NC_ + c)) * E_;
    const bf16_t* Pr = P + (((size_t)(b * NC_ + c)) * CCH + tl) * CCH;
    float s = __bfloat162float(qr[tid]) * zr[tid]
            + __bfloat162float(qr[tid + 256]) * zr[tid + 256]
            + __bfloat162float(Pr[tid]);
    red[tid] = s;
    __syncthreads();
    for (int st = 128; st > 0; st >>= 1) { if (tid < st) red[tid] += red[tid + st]; __syncthreads(); }
    if (tid == 0) invd[row] = 1.f / fmaxf(red[0], EPS_);
}

// ---------------------------------------------------------------------------
__global__ __launch_bounds__(256) void attnout_kernel(
    const short* __restrict__ qbf, const short* __restrict__ KV,
    const short* __restrict__ P, const short* __restrict__ vT,
    const float* __restrict__ invd, bf16_t* __restrict__ attn) {
    __shared__ __align__(16) short Al[128 * 32], Bl[128 * 32];
    GEMM_PROLOG
    int t0 = blockIdx.x * 128, i0 = blockIdx.y * 128, b = blockIdx.z;
    int c = t0 >> 8, tl0 = t0 & 255, bc = b * NC_ + c;
    gemm128(qbf + ((size_t)b * T_ + t0) * E_, E_,
            KV + ((size_t)bc * E_ + i0) * E_, E_, E_, Al, Bl, acc, wm, wn, wq, lane);
    gemm128(P + ((size_t)bc * CCH + tl0) * CCH, CCH,
            vT + ((size_t)b * E_ + i0) * T_ + c * CCH, T_, CCH, Al, Bl, acc, wm, wn, wq, lane);
    #pragma unroll
    for (int mt = 0; mt < 4; ++mt)
        #pragma unroll
        for (int r = 0; r < 4; ++r) {
            int t = t0 + wm + mt * 16 + quad * 4 + r;
            float sc = invd[(size_t)b * T_ + t];
            #pragma unroll
            for (int nt = 0; nt < 4; ++nt) {
                int col = i0 + wn + nt * 16 + m16;
                attn[((size_t)b * T_ + t) * E_ + col] = __float2bfloat16(acc[mt][nt][r] * sc);
            }
        }
}

// ---------------------------------------------------------------------------
__global__ __launch_bounds__(256) void outproj_kernel(
    const short* __restrict__ attn, const short* __restrict__ wbf_o,
    const float* __restrict__ ob, float* __restrict__ out) {
    __shared__ __align__(16) short Al[128 * 32], Bl[128 * 32];
    GEMM_PROLOG
    int t0 = blockIdx.x * 128, i0 = blockIdx.y * 128, b = blockIdx.z;
    gemm128(attn + ((size_t)b * T_ + t0) * E_, E_,
            wbf_o + (size_t)i0 * E_, E_, E_, Al, Bl, acc, wm, wn, wq, lane);
    #pragma unroll
    for (int mt = 0; mt < 4; ++mt)
        #pragma unroll
        for (int r = 0; r < 4; ++r) {
            int t = t0 + wm + mt * 16 + quad * 4 + r;
            #pragma unroll
            for (int nt = 0; nt < 4; ++nt) {
                int col = i0 + wn + nt * 16 + m16;
                out[((size_t)b * T_ + t) * E_ + col] = acc[mt][nt][r] + ob[col];
            }
        }
}

// ---------------------------------------------------------------------------
extern "C" void kernel_launch(void* const* d_in, const int* in_sizes, int n_in,
                              void* d_out, int out_size, void* d_ws, size_t ws_size,
                              hipStream_t stream) {
    const float* x    = (const float*)d_in[0];
    const float* toep = (const float*)d_in[1];
    const float* q_w  = (const float*)d_in[2];
    const float* q_b  = (const float*)d_in[3];
    const float* k_w  = (const float*)d_in[4];
    const float* k_b  = (const float*)d_in[5];
    const float* v_w  = (const float*)d_in[6];
    const float* v_b  = (const float*)d_in[7];
    const float* o_w  = (const float*)d_in[8];
    const float* o_b  = (const float*)d_in[9];

    const size_t NTE = (size_t)B_ * T_ * E_;          // 8388608
    char* base = (char*)d_ws;
    short* xbf  = (short*)base;  base += NTE * 2;
    short* wbf  = (short*)base;  base += (size_t)4 * E_ * E_ * 2;
    short* qraw = (short*)base;  base += NTE * 2;
    short* qbf  = (short*)base;  base += NTE * 2;
    short* kbf  = (short*)base;  base += NTE * 2;
    short* vbf  = (short*)base;  base += NTE * 2;
    short* kT   = (short*)base;  base += NTE * 2;
    short* vT   = (short*)base;  base += NTE * 2;
    short* KV   = (short*)base;  base += (size_t)B_ * NC_ * E_ * E_ * 2;
    short* P    = (short*)base;  base += (size_t)B_ * NC_ * CCH * CCH * 2;
    float* ksum = (float*)base;  base += (size_t)B_ * NC_ * E_ * 4;
    float* invd = (float*)base;  base += (size_t)B_ * T_ * 4;
    short* attn = xbf;           // xbf dead after proj_qkv: reuse for attn bf16
    float* out  = (float*)d_out;

    dim3 blk(256);
    prep_kernel<<<dim3(2560), blk, 0, stream>>>(q_w, k_w, v_w, o_w, wbf, x, xbf);
    proj_qkv_kernel<<<dim3(16, 4, 24), blk, 0, stream>>>(
        xbf, wbf, q_b, k_b, v_b, toep, (bf16_t*)qraw, (bf16_t*)kbf, (bf16_t*)vbf);
    softmax_ksum_kernel<<<dim3(B_ * T_ + 128), blk, 0, stream>>>(
        (const bf16_t*)qraw, (bf16_t*)qbf, (const bf16_t*)kbf, ksum);
    transpose_bf_kernel<<<dim3(32, 8, 16), blk, 0, stream>>>(kbf, vbf, kT, vT);
    kvp_kernel<<<dim3(1280), blk, 0, stream>>>(
        vT, kT, (bf16_t*)KV, qbf, kbf, (bf16_t*)P);
    scan2_kernel<<<dim3(8208), blk, 0, stream>>>((bf16_t*)KV, ksum);
    denom_kernel<<<dim3(B_ * T_), blk, 0, stream>>>(
        (const bf16_t*)qbf, ksum, (const bf16_t*)P, invd);
    attnout_kernel<<<dim3(16, 4, 8), blk, 0, stream>>>(
        qbf, KV, P, vT, invd, (bf16_t*)attn);
    outproj_kernel<<<dim3(16, 4, 8), blk, 0, stream>>>(
        attn, wbf + (size_t)3 * E_ * E_, o_b, out);
}

// Round 6
// 308.243 us; speedup vs baseline: 1.0376x; 1.0087x over previous
//
#include <hip/hip_runtime.h>
#include <hip/hip_bf16.h>
#include <math.h>
#include <stdint.h>

#define B_ 8
#define T_ 2048
#define E_ 512
#define CCH 256
#define NC_ 8
#define EPS_ 1e-3f
#define QSCALE 0.044194173824159216f   // 512^-0.5

typedef __attribute__((ext_vector_type(8))) short short8;
typedef __attribute__((ext_vector_type(4))) float f32x4;
typedef __hip_bfloat16 bf16_t;

__device__ __forceinline__ short f2bs(float x) {
    bf16_t h = __float2bfloat16(x);
    return __builtin_bit_cast(short, h);
}
__device__ __forceinline__ float bs2f(short s) {
    bf16_t h = __builtin_bit_cast(bf16_t, s);
    return __bfloat162float(h);
}

// async global->LDS, 16B per lane; LDS dest is wave-uniform base + lane*16
__device__ __forceinline__ void async16(const void* g, void* l) {
    __builtin_amdgcn_global_load_lds(
        (const __attribute__((address_space(1))) unsigned int*)(unsigned long long)(uintptr_t)g,
        (__attribute__((address_space(3))) unsigned int*)(unsigned int)(uintptr_t)l,
        16, 0, 0);
}

// ---------------------------------------------------------------------------
// GEMM core: C[128x128] += A[128xK] * (B^T[128xK])^T, bf16 in, fp32 acc.
// Operands row-major, K contiguous. 256 threads = 4 waves 2x2; each wave 64x64
// = 4x4 MFMA 16x16x32 tiles. BK=32, DOUBLE-BUFFERED (32KB LDS, 5 blk/CU):
//   iter top: barrier (compiler's vmcnt(0) drains DMA of tile i) -> issue DMA
//   for tile i+1 into other buffer -> ds_read+MFMA tile i. One barrier/iter;
//   DMA latency overlaps compute.
// LDS per buffer: A then B, each 8 windows of 512 shorts: [kchunk(4)][row(16)][16B]
//   -> fragment reads are 16-lane-consecutive 16B chunks (2-way alias = free).
// ---------------------------------------------------------------------------
__device__ __forceinline__ void gemm128(const short* __restrict__ Ag, int lda,
                                        const short* __restrict__ Bg, int ldb, int K,
                                        short* L, f32x4 acc[4][4],
                                        int wm, int wn, int wq, int lane) {
    int m16 = lane & 15, quad = lane >> 4;
    int r16 = lane & 15, c4 = quad * 8;
    int nstep = K >> 5;
    __syncthreads();                       // WAR guard for back-to-back calls
    #pragma unroll
    for (int w = 0; w < 2; ++w) {
        int win = wq + w * 4;
        async16(Ag + (size_t)(win * 16 + r16) * lda + c4, L + win * 512);
        async16(Bg + (size_t)(win * 16 + r16) * ldb + c4, L + 4096 + win * 512);
    }
    for (int i = 0; i < nstep; ++i) {
        int cur = (i & 1) << 13;           // 0 or 8192 shorts
        int nxt = 8192 - cur;
        __syncthreads();                   // drains DMA(i); orders reads of buf nxt
        if (i + 1 < nstep) {
            int k0 = (i + 1) << 5;
            #pragma unroll
            for (int w = 0; w < 2; ++w) {
                int win = wq + w * 4;
                async16(Ag + (size_t)(win * 16 + r16) * lda + k0 + c4, L + nxt + win * 512);
                async16(Bg + (size_t)(win * 16 + r16) * ldb + k0 + c4, L + nxt + 4096 + win * 512);
            }
        }
        const short* Ac = L + cur;
        const short* Bc = L + cur + 4096;
        short8 a[4], b[4];
        #pragma unroll
        for (int t = 0; t < 4; ++t)
            a[t] = *(const short8*)(Ac + (wm + t * 16) * 32 + quad * 128 + m16 * 8);
        #pragma unroll
        for (int t = 0; t < 4; ++t)
            b[t] = *(const short8*)(Bc + (wn + t * 16) * 32 + quad * 128 + m16 * 8);
        #pragma unroll
        for (int t = 0; t < 4; ++t)
            #pragma unroll
            for (int j = 0; j < 4; ++j)
                acc[t][j] = __builtin_amdgcn_mfma_f32_16x16x32_bf16(a[t], b[j], acc[t][j], 0, 0, 0);
    }
}

#define GEMM_PROLOG \
    int tid = threadIdx.x, lane = tid & 63, wq = tid >> 6; \
    int wm = (wq & 1) * 64, wn = (wq >> 1) * 64; \
    int m16 = lane & 15, quad = lane >> 4; \
    (void)tid; \
    f32x4 acc[4][4]; \
    { f32x4 zz = {0.f, 0.f, 0.f, 0.f}; \
      for (int i = 0; i < 4; ++i) for (int j = 0; j < 4; ++j) acc[i][j] = zz; }

// ---------------------------------------------------------------------------
// prep: blocks [0,512) cast weights fp32->bf16; blocks [512,2560) transpose x.
// ---------------------------------------------------------------------------
__global__ void prep_kernel(const float* __restrict__ qw, const float* __restrict__ kw,
                            const float* __restrict__ vw, const float* __restrict__ ow,
                            short* __restrict__ wbf,
                            const float* __restrict__ x, short* __restrict__ xbf) {
    int bid = blockIdx.x;
    int tid = threadIdx.x;
    if (bid < 512) {
        size_t idx8 = ((size_t)bid * 256 + tid) * 8;
        int sel = (int)(idx8 >> 18);
        size_t off = idx8 & ((1u << 18) - 1);
        const float* src = sel == 0 ? qw : sel == 1 ? kw : sel == 2 ? vw : ow;
        const float4* sp = (const float4*)(src + off);
        float4 a = sp[0], b = sp[1];
        short8 g;
        g[0] = f2bs(a.x); g[1] = f2bs(a.y); g[2] = f2bs(a.z); g[3] = f2bs(a.w);
        g[4] = f2bs(b.x); g[5] = f2bs(b.y); g[6] = f2bs(b.z); g[7] = f2bs(b.w);
        *(short8*)(wbf + idx8) = g;
        return;
    }
    bid -= 512;
    __shared__ __align__(16) float S[64][68];
    int t0 = (bid & 31) * 64, e0 = ((bid >> 5) & 7) * 64, b = bid >> 8;
    const float* src = x + ((size_t)b * E_ + e0) * T_ + t0;
    short* dst = xbf + ((size_t)b * T_ + t0) * E_ + e0;
    #pragma unroll
    for (int p = 0; p < 2; ++p) {
        int el = p * 32 + (tid >> 3), tc = (tid & 7) * 8;
        const float4* sp = (const float4*)(src + (size_t)el * T_ + tc);
        *(float4*)&S[el][tc] = sp[0];
        *(float4*)&S[el][tc + 4] = sp[1];
    }
    __syncthreads();
    #pragma unroll
    for (int p = 0; p < 2; ++p) {
        int tl = p * 32 + (tid >> 3), ec = (tid & 7) * 8;
        short8 g;
        #pragma unroll
        for (int j = 0; j < 8; ++j) g[j] = f2bs(S[ec + j][tl]);
        *(short8*)(dst + (size_t)tl * E_ + ec) = g;
    }
}

// ---------------------------------------------------------------------------
__global__ void transpose_bf_kernel(const short* __restrict__ k, const short* __restrict__ v,
                                    short* __restrict__ kT, short* __restrict__ vT) {
    __shared__ __align__(16) short S[64][72];
    int tid = threadIdx.x;
    int t0 = blockIdx.x * 64, e0 = blockIdx.y * 64;
    int b = blockIdx.z >> 1, which = blockIdx.z & 1;
    const short* src = (which ? v : k) + ((size_t)b * T_ + t0) * E_ + e0;
    short* dst = (which ? vT : kT) + ((size_t)b * E_ + e0) * T_ + t0;
    #pragma unroll
    for (int p = 0; p < 2; ++p) {
        int tl = p * 32 + (tid >> 3), ec = (tid & 7) * 8;
        *(short8*)&S[tl][ec] = *(const short8*)(src + (size_t)tl * E_ + ec);
    }
    __syncthreads();
    #pragma unroll
    for (int p = 0; p < 2; ++p) {
        int er = p * 32 + (tid >> 3), tc = (tid & 7) * 8;
        short8 g;
        #pragma unroll
        for (int j = 0; j < 8; ++j) g[j] = S[tc + j][er];
        *(short8*)(dst + (size_t)er * T_ + tc) = g;
    }
}

// ---------------------------------------------------------------------------
__global__ __launch_bounds__(256) void proj_qkv_kernel(
    const short* __restrict__ xbf, const short* __restrict__ wbf,
    const float* __restrict__ qb, const float* __restrict__ kb, const float* __restrict__ vb,
    const float* __restrict__ toep,
    bf16_t* __restrict__ qraw, bf16_t* __restrict__ kout, bf16_t* __restrict__ vout) {
    __shared__ __align__(16) short L[16384];
    GEMM_PROLOG
    int t0 = blockIdx.x * 128, i0 = blockIdx.y * 128;
    int b = blockIdx.z / 3, sel = blockIdx.z % 3;
    const short* Ag = xbf + ((size_t)b * T_ + t0) * E_;
    const short* Bg = wbf + (size_t)sel * E_ * E_ + (size_t)i0 * E_;
    gemm128(Ag, E_, Bg, E_, E_, L, acc, wm, wn, wq, lane);
    const float* bias = (sel == 0) ? qb : (sel == 1) ? kb : vb;
    #pragma unroll
    for (int mt = 0; mt < 4; ++mt)
        #pragma unroll
        for (int r = 0; r < 4; ++r) {
            int t = t0 + wm + mt * 16 + quad * 4 + r;
            size_t rowoff = ((size_t)b * T_ + t) * E_;
            float tw = toep[t];
            #pragma unroll
            for (int nt = 0; nt < 4; ++nt) {
                int col = i0 + wn + nt * 16 + m16;
                float vv = acc[mt][nt][r] + bias[col];
                if (sel == 0) qraw[rowoff + col] = __float2bfloat16(vv);
                else if (sel == 1) kout[rowoff + col] = __float2bfloat16(expf(vv));
                else vout[rowoff + col] = __float2bfloat16(vv * tw);
            }
        }
}

// ---------------------------------------------------------------------------
// blocks [0,16384): softmax over q rows; blocks [16384,16512): per-chunk ksum
// ---------------------------------------------------------------------------
__global__ void softmax_ksum_kernel(const bf16_t* __restrict__ qraw, bf16_t* __restrict__ qbf,
                                    const bf16_t* __restrict__ k, float* __restrict__ ks) {
    int bid = blockIdx.x, tid = threadIdx.x;
    if (bid >= B_ * T_) {
        int r = bid - B_ * T_;             // 128 blocks: (bc=64, half=2)
        int bc = r >> 1, b = bc >> 3, c = bc & 7;
        int e = (r & 1) * 256 + tid;
        const bf16_t* kp = k + ((size_t)b * T_ + (size_t)c * CCH) * E_ + e;
        float s = 0.f;
        for (int t = 0; t < CCH; ++t) s += __bfloat162float(kp[(size_t)t * E_]);
        ks[(size_t)bc * E_ + e] = s;
        return;
    }
    __shared__ float red[256];
    const bf16_t* p = qraw + (size_t)bid * E_;
    float v0 = __bfloat162float(p[tid]), v1 = __bfloat162float(p[tid + 256]);
    red[tid] = fmaxf(v0, v1);
    __syncthreads();
    for (int s = 128; s > 0; s >>= 1) { if (tid < s) red[tid] = fmaxf(red[tid], red[tid + s]); __syncthreads(); }
    float m = red[0];
    __syncthreads();
    float e0 = expf(v0 - m), e1 = expf(v1 - m);
    red[tid] = e0 + e1;
    __syncthreads();
    for (int s = 128; s > 0; s >>= 1) { if (tid < s) red[tid] += red[tid + s]; __syncthreads(); }
    float inv = QSCALE / red[0];
    qbf[(size_t)bid * E_ + tid] = __float2bfloat16(e0 * inv);
    qbf[(size_t)bid * E_ + tid + 256] = __float2bfloat16(e1 * inv);
}

// ---------------------------------------------------------------------------
// blocks [0,1024): chunk KV^T; blocks [1024,1280): intra-chunk P matrix
// ---------------------------------------------------------------------------
__global__ __launch_bounds__(256) void kvp_kernel(
    const short* __restrict__ vT, const short* __restrict__ kT, bf16_t* __restrict__ KV,
    const short* __restrict__ qbf, const short* __restrict__ kbf, bf16_t* __restrict__ P) {
    __shared__ __align__(16) short L[16384];
    int bid = blockIdx.x;
    if (bid < 1024) {
        GEMM_PROLOG
        int ev0 = (bid & 3) * 128, ek0 = ((bid >> 2) & 3) * 128;
        int bc = bid >> 4, b = bc >> 3, c = bc & 7;
        const short* Ag = vT + ((size_t)b * E_ + ev0) * T_ + c * CCH;
        const short* Bg = kT + ((size_t)b * E_ + ek0) * T_ + c * CCH;
        gemm128(Ag, T_, Bg, T_, CCH, L, acc, wm, wn, wq, lane);
        #pragma unroll
        for (int mt = 0; mt < 4; ++mt)
            #pragma unroll
            for (int r = 0; r < 4; ++r) {
                int ev = ev0 + wm + mt * 16 + quad * 4 + r;
                #pragma unroll
                for (int nt = 0; nt < 4; ++nt) {
                    int ek = ek0 + wn + nt * 16 + m16;
                    KV[((size_t)bc * E_ + ev) * E_ + ek] = __float2bfloat16(acc[mt][nt][r]);
                }
            }
        return;
    }
    bid -= 1024;
    int tj0 = (bid & 1) * 128, ti0 = ((bid >> 1) & 1) * 128;
    int bc = bid >> 2, b = bc >> 3, c = bc & 7;
    short* Pp = (short*)P + (size_t)bc * CCH * CCH;
    if (tj0 > ti0) {           // above diagonal: zero-fill (ws is poisoned)
        short8 z8 = {0, 0, 0, 0, 0, 0, 0, 0};
        for (int i = threadIdx.x; i < 128 * 128 / 8; i += 256) {
            int row = i >> 4, colc = (i * 8) & 127;
            *(short8*)(Pp + (size_t)(ti0 + row) * CCH + tj0 + colc) = z8;
        }
        return;
    }
    GEMM_PROLOG
    const short* Ag = qbf + ((size_t)b * T_ + c * CCH + ti0) * E_;
    const short* Bg = kbf + ((size_t)b * T_ + c * CCH + tj0) * E_;
    gemm128(Ag, E_, Bg, E_, E_, L, acc, wm, wn, wq, lane);
    #pragma unroll
    for (int mt = 0; mt < 4; ++mt)
        #pragma unroll
        for (int r = 0; r < 4; ++r) {
            int row = ti0 + wm + mt * 16 + quad * 4 + r;
            #pragma unroll
            for (int nt = 0; nt < 4; ++nt) {
                int col = tj0 + wn + nt * 16 + m16;
                float vv = (col <= row) ? acc[mt][nt][r] : 0.f;
                ((bf16_t*)Pp)[(size_t)row * CCH + col] = __float2bfloat16(vv);
            }
        }
}

// ---------------------------------------------------------------------------
// blocks [0,1024): exclusive chunk-scan of KV (bf16, 8 elem/thread);
// blocks [1024,1040): fp32 exclusive chunk-scan of ksum
// ---------------------------------------------------------------------------
__global__ void scan2_kernel(short* __restrict__ KV, float* __restrict__ ks) {
    int bid = blockIdx.x, tid = threadIdx.x;
    if (bid < 1024) {
        int gid = bid * 256 + tid;                 // B*E*E/8 = 262144 ids
        int b = gid >> 15;
        size_t idx = (size_t)(gid & 32767) * 8;
        short* p = KV + (size_t)b * NC_ * E_ * E_ + idx;
        float run[8] = {0.f, 0.f, 0.f, 0.f, 0.f, 0.f, 0.f, 0.f};
        #pragma unroll
        for (int c = 0; c < NC_; ++c) {
            short8 t8 = *(short8*)p;
            short8 o8;
            #pragma unroll
            for (int j = 0; j < 8; ++j) {
                float tv = bs2f(t8[j]);
                o8[j] = f2bs(run[j]);
                run[j] += tv;
            }
            *(short8*)p = o8;
            p += (size_t)E_ * E_;
        }
        return;
    }
    int gid = (bid - 1024) * 256 + tid;            // B*E = 4096 ids
    int b = gid >> 9, idx = gid & (E_ - 1);
    float run = 0.f;
    float* p = ks + (size_t)b * NC_ * E_ + idx;
    for (int c = 0; c < NC_; ++c) { float t = *p; *p = run; run += t; p += E_; }
}

// ---------------------------------------------------------------------------
__global__ void denom_kernel(const bf16_t* __restrict__ qbf, const float* __restrict__ z,
                             const bf16_t* __restrict__ P, float* __restrict__ invd) {
    __shared__ float red[256];
    int row = blockIdx.x, tid = threadIdx.x;
    int b = row >> 11, t = row & (T_ - 1);
    int c = t >> 8, tl = t & 255;
    const bf16_t* qr = qbf + (size_t)row * E_;
    const float* zr = z + ((size_t)(b * NC_ + c)) * E_;
    const bf16_t* Pr = P + (((size_t)(b * NC_ + c)) * CCH + tl) * CCH;
    float s = __bfloat162float(qr[tid]) * zr[tid]
            + __bfloat162float(qr[tid + 256]) * zr[tid + 256]
            + __bfloat162float(Pr[tid]);
    red[tid] = s;
    __syncthreads();
    for (int st = 128; st > 0; st >>= 1) { if (tid < st) red[tid] += red[tid + st]; __syncthreads(); }
    if (tid == 0) invd[row] = 1.f / fmaxf(red[0], EPS_);
}

// ---------------------------------------------------------------------------
__global__ __launch_bounds__(256) void attnout_kernel(
    const short* __restrict__ qbf, const short* __restrict__ KV,
    const short* __restrict__ P, const short* __restrict__ vT,
    const float* __restrict__ invd, bf16_t* __restrict__ attn) {
    __shared__ __align__(16) short L[16384];
    GEMM_PROLOG
    int t0 = blockIdx.x * 128, i0 = blockIdx.y * 128, b = blockIdx.z;
    int c = t0 >> 8, tl0 = t0 & 255, bc = b * NC_ + c;
    gemm128(qbf + ((size_t)b * T_ + t0) * E_, E_,
            KV + ((size_t)bc * E_ + i0) * E_, E_, E_, L, acc, wm, wn, wq, lane);
    gemm128(P + ((size_t)bc * CCH + tl0) * CCH, CCH,
            vT + ((size_t)b * E_ + i0) * T_ + c * CCH, T_, CCH, L, acc, wm, wn, wq, lane);
    #pragma unroll
    for (int mt = 0; mt < 4; ++mt)
        #pragma unroll
        for (int r = 0; r < 4; ++r) {
            int t = t0 + wm + mt * 16 + quad * 4 + r;
            float sc = invd[(size_t)b * T_ + t];
            #pragma unroll
            for (int nt = 0; nt < 4; ++nt) {
                int col = i0 + wn + nt * 16 + m16;
                attn[((size_t)b * T_ + t) * E_ + col] = __float2bfloat16(acc[mt][nt][r] * sc);
            }
        }
}

// ---------------------------------------------------------------------------
__global__ __launch_bounds__(256) void outproj_kernel(
    const short* __restrict__ attn, const short* __restrict__ wbf_o,
    const float* __restrict__ ob, float* __restrict__ out) {
    __shared__ __align__(16) short L[16384];
    GEMM_PROLOG
    int t0 = blockIdx.x * 128, i0 = blockIdx.y * 128, b = blockIdx.z;
    gemm128(attn + ((size_t)b * T_ + t0) * E_, E_,
            wbf_o + (size_t)i0 * E_, E_, E_, L, acc, wm, wn, wq, lane);
    #pragma unroll
    for (int mt = 0; mt < 4; ++mt)
        #pragma unroll
        for (int r = 0; r < 4; ++r) {
            int t = t0 + wm + mt * 16 + quad * 4 + r;
            #pragma unroll
            for (int nt = 0; nt < 4; ++nt) {
                int col = i0 + wn + nt * 16 + m16;
                out[((size_t)b * T_ + t) * E_ + col] = acc[mt][nt][r] + ob[col];
            }
        }
}

// ---------------------------------------------------------------------------
extern "C" void kernel_launch(void* const* d_in, const int* in_sizes, int n_in,
                              void* d_out, int out_size, void* d_ws, size_t ws_size,
                              hipStream_t stream) {
    const float* x    = (const float*)d_in[0];
    const float* toep = (const float*)d_in[1];
    const float* q_w  = (const float*)d_in[2];
    const float* q_b  = (const float*)d_in[3];
    const float* k_w  = (const float*)d_in[4];
    const float* k_b  = (const float*)d_in[5];
    const float* v_w  = (const float*)d_in[6];
    const float* v_b  = (const float*)d_in[7];
    const float* o_w  = (const float*)d_in[8];
    const float* o_b  = (const float*)d_in[9];

    const size_t NTE = (size_t)B_ * T_ * E_;          // 8388608
    char* base = (char*)d_ws;
    short* xbf  = (short*)base;  base += NTE * 2;
    short* wbf  = (short*)base;  base += (size_t)4 * E_ * E_ * 2;
    short* qraw = (short*)base;  base += NTE * 2;
    short* qbf  = (short*)base;  base += NTE * 2;
    short* kbf  = (short*)base;  base += NTE * 2;
    short* vbf  = (short*)base;  base += NTE * 2;
    short* kT   = (short*)base;  base += NTE * 2;
    short* vT   = (short*)base;  base += NTE * 2;
    short* KV   = (short*)base;  base += (size_t)B_ * NC_ * E_ * E_ * 2;
    short* P    = (short*)base;  base += (size_t)B_ * NC_ * CCH * CCH * 2;
    float* ksum = (float*)base;  base += (size_t)B_ * NC_ * E_ * 4;
    float* invd = (float*)base;  base += (size_t)B_ * T_ * 4;
    short* attn = xbf;           // xbf dead after proj_qkv: reuse for attn bf16
    float* out  = (float*)d_out;

    dim3 blk(256);
    prep_kernel<<<dim3(2560), blk, 0, stream>>>(q_w, k_w, v_w, o_w, wbf, x, xbf);
    proj_qkv_kernel<<<dim3(16, 4, 24), blk, 0, stream>>>(
        xbf, wbf, q_b, k_b, v_b, toep, (bf16_t*)qraw, (bf16_t*)kbf, (bf16_t*)vbf);
    softmax_ksum_kernel<<<dim3(B_ * T_ + 128), blk, 0, stream>>>(
        (const bf16_t*)qraw, (bf16_t*)qbf, (const bf16_t*)kbf, ksum);
    transpose_bf_kernel<<<dim3(32, 8, 16), blk, 0, stream>>>(kbf, vbf, kT, vT);
    kvp_kernel<<<dim3(1280), blk, 0, stream>>>(
        vT, kT, (bf16_t*)KV, qbf, kbf, (bf16_t*)P);
    scan2_kernel<<<dim3(1040), blk, 0, stream>>>(KV, ksum);
    denom_kernel<<<dim3(B_ * T_), blk, 0, stream>>>(
        (const bf16_t*)qbf, ksum, (const bf16_t*)P, invd);
    attnout_kernel<<<dim3(16, 4, 8), blk, 0, stream>>>(
        qbf, KV, P, vT, invd, (bf16_t*)attn);
    outproj_kernel<<<dim3(16, 4, 8), blk, 0, stream>>>(
        attn, wbf + (size_t)3 * E_ * E_, o_b, out);
}

// Round 7
// 275.532 us; speedup vs baseline: 1.1608x; 1.1187x over previous
//
#include <hip/hip_runtime.h>
#include <hip/hip_bf16.h>
#include <math.h>
#include <stdint.h>

#define B_ 8
#define T_ 2048
#define E_ 512
#define CCH 256
#define NC_ 8
#define EPS_ 1e-3f
#define QSCALE 0.044194173824159216f   // 512^-0.5

typedef __attribute__((ext_vector_type(8))) short short8;
typedef __attribute__((ext_vector_type(4))) float f32x4;
typedef __hip_bfloat16 bf16_t;

__device__ __forceinline__ short f2bs(float x) {
    bf16_t h = __float2bfloat16(x);
    return __builtin_bit_cast(short, h);
}
__device__ __forceinline__ float bs2f(short s) {
    bf16_t h = __builtin_bit_cast(bf16_t, s);
    return __bfloat162float(h);
}

// async global->LDS, 16B per lane; LDS dest is wave-uniform base + lane*16
__device__ __forceinline__ void async16(const void* g, void* l) {
    __builtin_amdgcn_global_load_lds(
        (const __attribute__((address_space(1))) unsigned int*)(unsigned long long)(uintptr_t)g,
        (__attribute__((address_space(3))) unsigned int*)(unsigned int)(uintptr_t)l,
        16, 0, 0);
}

// ---------------------------------------------------------------------------
// GEMM core: C[128x128] += A[128xK] * (B^T[128xK])^T, bf16 in, fp32 acc.
// Operands row-major, K contiguous. 256 threads = 4 waves 2x2; each wave 64x64
// = 4x4 MFMA 16x16x32 tiles. BK=64, single-buffer 32KB LDS (5 blk/CU).
// XOR-SWIZZLED LDS: row-major [row][8 chunks of 16B], chunk index XOR (row&7).
//   DMA lane l: global (row=R+(l>>3), chunk=(l&7)^(l>>3)), LDS dest l*16 ->
//   8 consecutive lanes cover 128B contiguous of one row (max coalescing);
//   stored chunk position is swizzled.
//   Frag read row m, k-chunk c: LDS addr m*64 + ((c^(m&7))*8) -> across 16
//   lanes all 8 chunk positions hit 2x each = 2-way bank alias = free.
// ---------------------------------------------------------------------------
__device__ __forceinline__ void gemm128(const short* __restrict__ Ag, int lda,
                                        const short* __restrict__ Bg, int ldb, int K,
                                        short* L, f32x4 acc[4][4],
                                        int wm, int wn, int wq, int lane) {
    int m16 = lane & 15, quad = lane >> 4;
    int lrow = lane >> 3;              // 0..7
    int lchunk = (lane & 7) ^ lrow;    // swizzled global 16B-chunk
    short* Bl = L + 8192;
    for (int k0 = 0; k0 < K; k0 += 64) {
        __syncthreads();               // WAR: all reads of prev tile done
        #pragma unroll
        for (int w = 0; w < 4; ++w) {
            int R = wq * 32 + w * 8;
            async16(Ag + (size_t)(R + lrow) * lda + k0 + lchunk * 8, L + R * 64);
            async16(Bg + (size_t)(R + lrow) * ldb + k0 + lchunk * 8, Bl + R * 64);
        }
        __syncthreads();               // drains DMA (compiler vmcnt(0))
        #pragma unroll
        for (int h = 0; h < 2; ++h) {
            int cs = ((h * 4 + quad) ^ (m16 & 7)) * 8;
            short8 a[4], b[4];
            #pragma unroll
            for (int t = 0; t < 4; ++t)
                a[t] = *(const short8*)(L + (wm + t * 16 + m16) * 64 + cs);
            #pragma unroll
            for (int t = 0; t < 4; ++t)
                b[t] = *(const short8*)(Bl + (wn + t * 16 + m16) * 64 + cs);
            #pragma unroll
            for (int t = 0; t < 4; ++t)
                #pragma unroll
                for (int j = 0; j < 4; ++j)
                    acc[t][j] = __builtin_amdgcn_mfma_f32_16x16x32_bf16(a[t], b[j], acc[t][j], 0, 0, 0);
        }
    }
}

#define GEMM_PROLOG \
    int tid = threadIdx.x, lane = tid & 63, wq = tid >> 6; \
    int wm = (wq & 1) * 64, wn = (wq >> 1) * 64; \
    int m16 = lane & 15, quad = lane >> 4; \
    (void)tid; \
    f32x4 acc[4][4]; \
    { f32x4 zz = {0.f, 0.f, 0.f, 0.f}; \
      for (int i = 0; i < 4; ++i) for (int j = 0; j < 4; ++j) acc[i][j] = zz; }

// ---------------------------------------------------------------------------
// prep: blocks [0,512) cast weights fp32->bf16; blocks [512,2560) transpose x.
// ---------------------------------------------------------------------------
__global__ void prep_kernel(const float* __restrict__ qw, const float* __restrict__ kw,
                            const float* __restrict__ vw, const float* __restrict__ ow,
                            short* __restrict__ wbf,
                            const float* __restrict__ x, short* __restrict__ xbf) {
    int bid = blockIdx.x;
    int tid = threadIdx.x;
    if (bid < 512) {
        size_t idx8 = ((size_t)bid * 256 + tid) * 8;
        int sel = (int)(idx8 >> 18);
        size_t off = idx8 & ((1u << 18) - 1);
        const float* src = sel == 0 ? qw : sel == 1 ? kw : sel == 2 ? vw : ow;
        const float4* sp = (const float4*)(src + off);
        float4 a = sp[0], b = sp[1];
        short8 g;
        g[0] = f2bs(a.x); g[1] = f2bs(a.y); g[2] = f2bs(a.z); g[3] = f2bs(a.w);
        g[4] = f2bs(b.x); g[5] = f2bs(b.y); g[6] = f2bs(b.z); g[7] = f2bs(b.w);
        *(short8*)(wbf + idx8) = g;
        return;
    }
    bid -= 512;
    __shared__ __align__(16) float S[64][68];
    int t0 = (bid & 31) * 64, e0 = ((bid >> 5) & 7) * 64, b = bid >> 8;
    const float* src = x + ((size_t)b * E_ + e0) * T_ + t0;
    short* dst = xbf + ((size_t)b * T_ + t0) * E_ + e0;
    #pragma unroll
    for (int p = 0; p < 2; ++p) {
        int el = p * 32 + (tid >> 3), tc = (tid & 7) * 8;
        const float4* sp = (const float4*)(src + (size_t)el * T_ + tc);
        *(float4*)&S[el][tc] = sp[0];
        *(float4*)&S[el][tc + 4] = sp[1];
    }
    __syncthreads();
    #pragma unroll
    for (int p = 0; p < 2; ++p) {
        int tl = p * 32 + (tid >> 3), ec = (tid & 7) * 8;
        short8 g;
        #pragma unroll
        for (int j = 0; j < 8; ++j) g[j] = f2bs(S[ec + j][tl]);
        *(short8*)(dst + (size_t)tl * E_ + ec) = g;
    }
}

// ---------------------------------------------------------------------------
__global__ void transpose_bf_kernel(const short* __restrict__ k, const short* __restrict__ v,
                                    short* __restrict__ kT, short* __restrict__ vT) {
    __shared__ __align__(16) short S[64][72];
    int tid = threadIdx.x;
    int t0 = blockIdx.x * 64, e0 = blockIdx.y * 64;
    int b = blockIdx.z >> 1, which = blockIdx.z & 1;
    const short* src = (which ? v : k) + ((size_t)b * T_ + t0) * E_ + e0;
    short* dst = (which ? vT : kT) + ((size_t)b * E_ + e0) * T_ + t0;
    #pragma unroll
    for (int p = 0; p < 2; ++p) {
        int tl = p * 32 + (tid >> 3), ec = (tid & 7) * 8;
        *(short8*)&S[tl][ec] = *(const short8*)(src + (size_t)tl * E_ + ec);
    }
    __syncthreads();
    #pragma unroll
    for (int p = 0; p < 2; ++p) {
        int er = p * 32 + (tid >> 3), tc = (tid & 7) * 8;
        short8 g;
        #pragma unroll
        for (int j = 0; j < 8; ++j) g[j] = S[tc + j][er];
        *(short8*)(dst + (size_t)er * T_ + tc) = g;
    }
}

// ---------------------------------------------------------------------------
__global__ __launch_bounds__(256) void proj_qkv_kernel(
    const short* __restrict__ xbf, const short* __restrict__ wbf,
    const float* __restrict__ qb, const float* __restrict__ kb, const float* __restrict__ vb,
    const float* __restrict__ toep,
    bf16_t* __restrict__ qraw, bf16_t* __restrict__ kout, bf16_t* __restrict__ vout) {
    __shared__ __align__(16) short L[16384];
    GEMM_PROLOG
    int t0 = blockIdx.x * 128, i0 = blockIdx.y * 128;
    int b = blockIdx.z / 3, sel = blockIdx.z % 3;
    const short* Ag = xbf + ((size_t)b * T_ + t0) * E_;
    const short* Bg = wbf + (size_t)sel * E_ * E_ + (size_t)i0 * E_;
    gemm128(Ag, E_, Bg, E_, E_, L, acc, wm, wn, wq, lane);
    const float* bias = (sel == 0) ? qb : (sel == 1) ? kb : vb;
    #pragma unroll
    for (int mt = 0; mt < 4; ++mt)
        #pragma unroll
        for (int r = 0; r < 4; ++r) {
            int t = t0 + wm + mt * 16 + quad * 4 + r;
            size_t rowoff = ((size_t)b * T_ + t) * E_;
            float tw = toep[t];
            #pragma unroll
            for (int nt = 0; nt < 4; ++nt) {
                int col = i0 + wn + nt * 16 + m16;
                float vv = acc[mt][nt][r] + bias[col];
                if (sel == 0) qraw[rowoff + col] = __float2bfloat16(vv);
                else if (sel == 1) kout[rowoff + col] = __float2bfloat16(expf(vv));
                else vout[rowoff + col] = __float2bfloat16(vv * tw);
            }
        }
}

// ---------------------------------------------------------------------------
// blocks [0,16384): softmax over q rows; blocks [16384,16512): per-chunk ksum
// ---------------------------------------------------------------------------
__global__ void softmax_ksum_kernel(const bf16_t* __restrict__ qraw, bf16_t* __restrict__ qbf,
                                    const bf16_t* __restrict__ k, float* __restrict__ ks) {
    int bid = blockIdx.x, tid = threadIdx.x;
    if (bid >= B_ * T_) {
        int r = bid - B_ * T_;             // 128 blocks: (bc=64, half=2)
        int bc = r >> 1, b = bc >> 3, c = bc & 7;
        int e = (r & 1) * 256 + tid;
        const bf16_t* kp = k + ((size_t)b * T_ + (size_t)c * CCH) * E_ + e;
        float s = 0.f;
        for (int t = 0; t < CCH; ++t) s += __bfloat162float(kp[(size_t)t * E_]);
        ks[(size_t)bc * E_ + e] = s;
        return;
    }
    __shared__ float red[256];
    const bf16_t* p = qraw + (size_t)bid * E_;
    float v0 = __bfloat162float(p[tid]), v1 = __bfloat162float(p[tid + 256]);
    red[tid] = fmaxf(v0, v1);
    __syncthreads();
    for (int s = 128; s > 0; s >>= 1) { if (tid < s) red[tid] = fmaxf(red[tid], red[tid + s]); __syncthreads(); }
    float m = red[0];
    __syncthreads();
    float e0 = expf(v0 - m), e1 = expf(v1 - m);
    red[tid] = e0 + e1;
    __syncthreads();
    for (int s = 128; s > 0; s >>= 1) { if (tid < s) red[tid] += red[tid + s]; __syncthreads(); }
    float inv = QSCALE / red[0];
    qbf[(size_t)bid * E_ + tid] = __float2bfloat16(e0 * inv);
    qbf[(size_t)bid * E_ + tid + 256] = __float2bfloat16(e1 * inv);
}

// ---------------------------------------------------------------------------
// blocks [0,1024): chunk KV^T; blocks [1024,1280): intra-chunk P matrix
// ---------------------------------------------------------------------------
__global__ __launch_bounds__(256) void kvp_kernel(
    const short* __restrict__ vT, const short* __restrict__ kT, bf16_t* __restrict__ KV,
    const short* __restrict__ qbf, const short* __restrict__ kbf, bf16_t* __restrict__ P) {
    __shared__ __align__(16) short L[16384];
    int bid = blockIdx.x;
    if (bid < 1024) {
        GEMM_PROLOG
        int ev0 = (bid & 3) * 128, ek0 = ((bid >> 2) & 3) * 128;
        int bc = bid >> 4, b = bc >> 3, c = bc & 7;
        const short* Ag = vT + ((size_t)b * E_ + ev0) * T_ + c * CCH;
        const short* Bg = kT + ((size_t)b * E_ + ek0) * T_ + c * CCH;
        gemm128(Ag, T_, Bg, T_, CCH, L, acc, wm, wn, wq, lane);
        #pragma unroll
        for (int mt = 0; mt < 4; ++mt)
            #pragma unroll
            for (int r = 0; r < 4; ++r) {
                int ev = ev0 + wm + mt * 16 + quad * 4 + r;
                #pragma unroll
                for (int nt = 0; nt < 4; ++nt) {
                    int ek = ek0 + wn + nt * 16 + m16;
                    KV[((size_t)bc * E_ + ev) * E_ + ek] = __float2bfloat16(acc[mt][nt][r]);
                }
            }
        return;
    }
    bid -= 1024;
    int tj0 = (bid & 1) * 128, ti0 = ((bid >> 1) & 1) * 128;
    int bc = bid >> 2, b = bc >> 3, c = bc & 7;
    short* Pp = (short*)P + (size_t)bc * CCH * CCH;
    if (tj0 > ti0) {           // above diagonal: zero-fill (ws is poisoned)
        short8 z8 = {0, 0, 0, 0, 0, 0, 0, 0};
        for (int i = threadIdx.x; i < 128 * 128 / 8; i += 256) {
            int row = i >> 4, colc = (i * 8) & 127;
            *(short8*)(Pp + (size_t)(ti0 + row) * CCH + tj0 + colc) = z8;
        }
        return;
    }
    GEMM_PROLOG
    const short* Ag = qbf + ((size_t)b * T_ + c * CCH + ti0) * E_;
    const short* Bg = kbf + ((size_t)b * T_ + c * CCH + tj0) * E_;
    gemm128(Ag, E_, Bg, E_, E_, L, acc, wm, wn, wq, lane);
    #pragma unroll
    for (int mt = 0; mt < 4; ++mt)
        #pragma unroll
        for (int r = 0; r < 4; ++r) {
            int row = ti0 + wm + mt * 16 + quad * 4 + r;
            #pragma unroll
            for (int nt = 0; nt < 4; ++nt) {
                int col = tj0 + wn + nt * 16 + m16;
                float vv = (col <= row) ? acc[mt][nt][r] : 0.f;
                ((bf16_t*)Pp)[(size_t)row * CCH + col] = __float2bfloat16(vv);
            }
        }
}

// ---------------------------------------------------------------------------
// blocks [0,1024): exclusive chunk-scan of KV (bf16, 8 elem/thread);
// blocks [1024,1040): fp32 exclusive chunk-scan of ksum
// ---------------------------------------------------------------------------
__global__ void scan2_kernel(short* __restrict__ KV, float* __restrict__ ks) {
    int bid = blockIdx.x, tid = threadIdx.x;
    if (bid < 1024) {
        int gid = bid * 256 + tid;                 // B*E*E/8 = 262144 ids
        int b = gid >> 15;
        size_t idx = (size_t)(gid & 32767) * 8;
        short* p = KV + (size_t)b * NC_ * E_ * E_ + idx;
        float run[8] = {0.f, 0.f, 0.f, 0.f, 0.f, 0.f, 0.f, 0.f};
        #pragma unroll
        for (int c = 0; c < NC_; ++c) {
            short8 t8 = *(short8*)p;
            short8 o8;
            #pragma unroll
            for (int j = 0; j < 8; ++j) {
                float tv = bs2f(t8[j]);
                o8[j] = f2bs(run[j]);
                run[j] += tv;
            }
            *(short8*)p = o8;
            p += (size_t)E_ * E_;
        }
        return;
    }
    int gid = (bid - 1024) * 256 + tid;            // B*E = 4096 ids
    int b = gid >> 9, idx = gid & (E_ - 1);
    float run = 0.f;
    float* p = ks + (size_t)b * NC_ * E_ + idx;
    for (int c = 0; c < NC_; ++c) { float t = *p; *p = run; run += t; p += E_; }
}

// ---------------------------------------------------------------------------
__global__ void denom_kernel(const bf16_t* __restrict__ qbf, const float* __restrict__ z,
                             const bf16_t* __restrict__ P, float* __restrict__ invd) {
    __shared__ float red[256];
    int row = blockIdx.x, tid = threadIdx.x;
    int b = row >> 11, t = row & (T_ - 1);
    int c = t >> 8, tl = t & 255;
    const bf16_t* qr = qbf + (size_t)row * E_;
    const float* zr = z + ((size_t)(b * NC_ + c)) * E_;
    const bf16_t* Pr = P + (((size_t)(b * NC_ + c)) * CCH + tl) * CCH;
    float s = __bfloat162float(qr[tid]) * zr[tid]
            + __bfloat162float(qr[tid + 256]) * zr[tid + 256]
            + __bfloat162float(Pr[tid]);
    red[tid] = s;
    __syncthreads();
    for (int st = 128; st > 0; st >>= 1) { if (tid < st) red[tid] += red[tid + st]; __syncthreads(); }
    if (tid == 0) invd[row] = 1.f / fmaxf(red[0], EPS_);
}

// ---------------------------------------------------------------------------
__global__ __launch_bounds__(256) void attnout_kernel(
    const short* __restrict__ qbf, const short* __restrict__ KV,
    const short* __restrict__ P, const short* __restrict__ vT,
    const float* __restrict__ invd, bf16_t* __restrict__ attn) {
    __shared__ __align__(16) short L[16384];
    GEMM_PROLOG
    int t0 = blockIdx.x * 128, i0 = blockIdx.y * 128, b = blockIdx.z;
    int c = t0 >> 8, tl0 = t0 & 255, bc = b * NC_ + c;
    gemm128(qbf + ((size_t)b * T_ + t0) * E_, E_,
            KV + ((size_t)bc * E_ + i0) * E_, E_, E_, L, acc, wm, wn, wq, lane);
    gemm128(P + ((size_t)bc * CCH + tl0) * CCH, CCH,
            vT + ((size_t)b * E_ + i0) * T_ + c * CCH, T_, CCH, L, acc, wm, wn, wq, lane);
    #pragma unroll
    for (int mt = 0; mt < 4; ++mt)
        #pragma unroll
        for (int r = 0; r < 4; ++r) {
            int t = t0 + wm + mt * 16 + quad * 4 + r;
            float sc = invd[(size_t)b * T_ + t];
            #pragma unroll
            for (int nt = 0; nt < 4; ++nt) {
                int col = i0 + wn + nt * 16 + m16;
                attn[((size_t)b * T_ + t) * E_ + col] = __float2bfloat16(acc[mt][nt][r] * sc);
            }
        }
}

// ---------------------------------------------------------------------------
__global__ __launch_bounds__(256) void outproj_kernel(
    const short* __restrict__ attn, const short* __restrict__ wbf_o,
    const float* __restrict__ ob, float* __restrict__ out) {
    __shared__ __align__(16) short L[16384];
    GEMM_PROLOG
    int t0 = blockIdx.x * 128, i0 = blockIdx.y * 128, b = blockIdx.z;
    gemm128(attn + ((size_t)b * T_ + t0) * E_, E_,
            wbf_o + (size_t)i0 * E_, E_, E_, L, acc, wm, wn, wq, lane);
    #pragma unroll
    for (int mt = 0; mt < 4; ++mt)
        #pragma unroll
        for (int r = 0; r < 4; ++r) {
            int t = t0 + wm + mt * 16 + quad * 4 + r;
            #pragma unroll
            for (int nt = 0; nt < 4; ++nt) {
                int col = i0 + wn + nt * 16 + m16;
                out[((size_t)b * T_ + t) * E_ + col] = acc[mt][nt][r] + ob[col];
            }
        }
}

// ---------------------------------------------------------------------------
extern "C" void kernel_launch(void* const* d_in, const int* in_sizes, int n_in,
                              void* d_out, int out_size, void* d_ws, size_t ws_size,
                              hipStream_t stream) {
    const float* x    = (const float*)d_in[0];
    const float* toep = (const float*)d_in[1];
    const float* q_w  = (const float*)d_in[2];
    const float* q_b  = (const float*)d_in[3];
    const float* k_w  = (const float*)d_in[4];
    const float* k_b  = (const float*)d_in[5];
    const float* v_w  = (const float*)d_in[6];
    const float* v_b  = (const float*)d_in[7];
    const float* o_w  = (const float*)d_in[8];
    const float* o_b  = (const float*)d_in[9];

    const size_t NTE = (size_t)B_ * T_ * E_;          // 8388608
    char* base = (char*)d_ws;
    short* xbf  = (short*)base;  base += NTE * 2;
    short* wbf  = (short*)base;  base += (size_t)4 * E_ * E_ * 2;
    short* qraw = (short*)base;  base += NTE * 2;
    short* qbf  = (short*)base;  base += NTE * 2;
    short* kbf  = (short*)base;  base += NTE * 2;
    short* vbf  = (short*)base;  base += NTE * 2;
    short* kT   = (short*)base;  base += NTE * 2;
    short* vT   = (short*)base;  base += NTE * 2;
    short* KV   = (short*)base;  base += (size_t)B_ * NC_ * E_ * E_ * 2;
    short* P    = (short*)base;  base += (size_t)B_ * NC_ * CCH * CCH * 2;
    float* ksum = (float*)base;  base += (size_t)B_ * NC_ * E_ * 4;
    float* invd = (float*)base;  base += (size_t)B_ * T_ * 4;
    short* attn = xbf;           // xbf dead after proj_qkv: reuse for attn bf16
    float* out  = (float*)d_out;

    dim3 blk(256);
    prep_kernel<<<dim3(2560), blk, 0, stream>>>(q_w, k_w, v_w, o_w, wbf, x, xbf);
    proj_qkv_kernel<<<dim3(16, 4, 24), blk, 0, stream>>>(
        xbf, wbf, q_b, k_b, v_b, toep, (bf16_t*)qraw, (bf16_t*)kbf, (bf16_t*)vbf);
    softmax_ksum_kernel<<<dim3(B_ * T_ + 128), blk, 0, stream>>>(
        (const bf16_t*)qraw, (bf16_t*)qbf, (const bf16_t*)kbf, ksum);
    transpose_bf_kernel<<<dim3(32, 8, 16), blk, 0, stream>>>(kbf, vbf, kT, vT);
    kvp_kernel<<<dim3(1280), blk, 0, stream>>>(
        vT, kT, (bf16_t*)KV, qbf, kbf, (bf16_t*)P);
    scan2_kernel<<<dim3(1040), blk, 0, stream>>>(KV, ksum);
    denom_kernel<<<dim3(B_ * T_), blk, 0, stream>>>(
        (const bf16_t*)qbf, ksum, (const bf16_t*)P, invd);
    attnout_kernel<<<dim3(16, 4, 8), blk, 0, stream>>>(
        qbf, KV, P, vT, invd, (bf16_t*)attn);
    outproj_kernel<<<dim3(16, 4, 8), blk, 0, stream>>>(
        attn, wbf + (size_t)3 * E_ * E_, o_b, out);
}

// Round 8
// 260.537 us; speedup vs baseline: 1.2276x; 1.0576x over previous
//
#include <hip/hip_runtime.h>
#include <hip/hip_bf16.h>
#include <math.h>
#include <stdint.h>

#define B_ 8
#define T_ 2048
#define E_ 512
#define CCH 256
#define NC_ 8
#define EPS_ 1e-3f
#define QSCALE 0.044194173824159216f   // 512^-0.5

typedef __attribute__((ext_vector_type(8))) short short8;
typedef __attribute__((ext_vector_type(4))) short short4v;
typedef __attribute__((ext_vector_type(4))) float f32x4;
typedef __hip_bfloat16 bf16_t;

__device__ __forceinline__ short f2bs(float x) {
    bf16_t h = __float2bfloat16(x);
    return __builtin_bit_cast(short, h);
}
__device__ __forceinline__ float bs2f(short s) {
    bf16_t h = __builtin_bit_cast(bf16_t, s);
    return __bfloat162float(h);
}

// async global->LDS, 16B per lane; LDS dest is wave-uniform base + lane*16
__device__ __forceinline__ void async16(const void* g, void* l) {
    __builtin_amdgcn_global_load_lds(
        (const __attribute__((address_space(1))) unsigned int*)(unsigned long long)(uintptr_t)g,
        (__attribute__((address_space(3))) unsigned int*)(unsigned int)(uintptr_t)l,
        16, 0, 0);
}

// ---------------------------------------------------------------------------
// GEMM core: C[128x128] += A[128xK] * (B^T[128xK])^T, bf16 in, fp32 acc.
// BK=64, single-buffer 32KB LDS, XOR-swizzled (see R7 notes): DMA 8-lane
// groups cover 128B-contiguous row segments; fragment reads 2-way alias only.
// ---------------------------------------------------------------------------
__device__ __forceinline__ void gemm128(const short* __restrict__ Ag, int lda,
                                        const short* __restrict__ Bg, int ldb, int K,
                                        short* L, f32x4 acc[4][4],
                                        int wm, int wn, int wq, int lane) {
    int m16 = lane & 15, quad = lane >> 4;
    int lrow = lane >> 3;              // 0..7
    int lchunk = (lane & 7) ^ lrow;    // swizzled global 16B-chunk
    short* Bl = L + 8192;
    for (int k0 = 0; k0 < K; k0 += 64) {
        __syncthreads();               // WAR: all reads of prev tile done
        #pragma unroll
        for (int w = 0; w < 4; ++w) {
            int R = wq * 32 + w * 8;
            async16(Ag + (size_t)(R + lrow) * lda + k0 + lchunk * 8, L + R * 64);
            async16(Bg + (size_t)(R + lrow) * ldb + k0 + lchunk * 8, Bl + R * 64);
        }
        __syncthreads();               // drains DMA (compiler vmcnt(0))
        #pragma unroll
        for (int h = 0; h < 2; ++h) {
            int cs = ((h * 4 + quad) ^ (m16 & 7)) * 8;
            short8 a[4], b[4];
            #pragma unroll
            for (int t = 0; t < 4; ++t)
                a[t] = *(const short8*)(L + (wm + t * 16 + m16) * 64 + cs);
            #pragma unroll
            for (int t = 0; t < 4; ++t)
                b[t] = *(const short8*)(Bl + (wn + t * 16 + m16) * 64 + cs);
            #pragma unroll
            for (int t = 0; t < 4; ++t)
                #pragma unroll
                for (int j = 0; j < 4; ++j)
                    acc[t][j] = __builtin_amdgcn_mfma_f32_16x16x32_bf16(a[t], b[j], acc[t][j], 0, 0, 0);
        }
    }
}

#define GEMM_PROLOG \
    int tid = threadIdx.x, lane = tid & 63, wq = tid >> 6; \
    int wm = (wq & 1) * 64, wn = (wq >> 1) * 64; \
    int m16 = lane & 15, quad = lane >> 4; \
    (void)tid; \
    f32x4 acc[4][4]; \
    { f32x4 zz = {0.f, 0.f, 0.f, 0.f}; \
      for (int i = 0; i < 4; ++i) for (int j = 0; j < 4; ++j) acc[i][j] = zz; }

// ---------------------------------------------------------------------------
// prep: blocks [0,512) cast weights fp32->bf16; blocks [512,2560) transpose x.
// ---------------------------------------------------------------------------
__global__ void prep_kernel(const float* __restrict__ qw, const float* __restrict__ kw,
                            const float* __restrict__ vw, const float* __restrict__ ow,
                            short* __restrict__ wbf,
                            const float* __restrict__ x, short* __restrict__ xbf) {
    int bid = blockIdx.x;
    int tid = threadIdx.x;
    if (bid < 512) {
        size_t idx8 = ((size_t)bid * 256 + tid) * 8;
        int sel = (int)(idx8 >> 18);
        size_t off = idx8 & ((1u << 18) - 1);
        const float* src = sel == 0 ? qw : sel == 1 ? kw : sel == 2 ? vw : ow;
        const float4* sp = (const float4*)(src + off);
        float4 a = sp[0], b = sp[1];
        short8 g;
        g[0] = f2bs(a.x); g[1] = f2bs(a.y); g[2] = f2bs(a.z); g[3] = f2bs(a.w);
        g[4] = f2bs(b.x); g[5] = f2bs(b.y); g[6] = f2bs(b.z); g[7] = f2bs(b.w);
        *(short8*)(wbf + idx8) = g;
        return;
    }
    bid -= 512;
    __shared__ __align__(16) float S[64][68];
    int t0 = (bid & 31) * 64, e0 = ((bid >> 5) & 7) * 64, b = bid >> 8;
    const float* src = x + ((size_t)b * E_ + e0) * T_ + t0;
    short* dst = xbf + ((size_t)b * T_ + t0) * E_ + e0;
    #pragma unroll
    for (int p = 0; p < 2; ++p) {
        int el = p * 32 + (tid >> 3), tc = (tid & 7) * 8;
        const float4* sp = (const float4*)(src + (size_t)el * T_ + tc);
        *(float4*)&S[el][tc] = sp[0];
        *(float4*)&S[el][tc + 4] = sp[1];
    }
    __syncthreads();
    #pragma unroll
    for (int p = 0; p < 2; ++p) {
        int tl = p * 32 + (tid >> 3), ec = (tid & 7) * 8;
        short8 g;
        #pragma unroll
        for (int j = 0; j < 8; ++j) g[j] = f2bs(S[ec + j][tl]);
        *(short8*)(dst + (size_t)tl * E_ + ec) = g;
    }
}

// ---------------------------------------------------------------------------
// fused q/k/v projections with fused k/v transpose in epilogue.
// sel0: qraw (T,E). sel1: k=exp -> kbf (T,E) AND kT (E,T). sel2: v*toep -> vT (E,T) only.
// Transposed stores: tile routed through LDS [col(128)][t(64)] stride 68, 2 passes.
// ---------------------------------------------------------------------------
__global__ __launch_bounds__(256) void proj_qkv_kernel(
    const short* __restrict__ xbf, const short* __restrict__ wbf,
    const float* __restrict__ qb, const float* __restrict__ kb, const float* __restrict__ vb,
    const float* __restrict__ toep,
    short* __restrict__ qraw, short* __restrict__ kbf,
    short* __restrict__ kT, short* __restrict__ vT) {
    __shared__ __align__(16) short L[16384];
    GEMM_PROLOG
    int t0 = blockIdx.x * 128, i0 = blockIdx.y * 128;
    int b = blockIdx.z / 3, sel = blockIdx.z % 3;
    const short* Ag = xbf + ((size_t)b * T_ + t0) * E_;
    const short* Bg = wbf + (size_t)sel * E_ * E_ + (size_t)i0 * E_;
    gemm128(Ag, E_, Bg, E_, E_, L, acc, wm, wn, wq, lane);
    const float* bias = (sel == 0) ? qb : (sel == 1) ? kb : vb;

    // epilogue values as bf16 bits: ov[mt][nt] holds r=0..3 (consecutive t)
    short4v ov[4][4];
    #pragma unroll
    for (int mt = 0; mt < 4; ++mt)
        #pragma unroll
        for (int r = 0; r < 4; ++r) {
            int t = t0 + wm + mt * 16 + quad * 4 + r;
            float tw = toep[t];
            #pragma unroll
            for (int nt = 0; nt < 4; ++nt) {
                int col = i0 + wn + nt * 16 + m16;
                float vv = acc[mt][nt][r] + bias[col];
                if (sel == 1) vv = expf(vv);
                if (sel == 2) vv = vv * tw;
                ov[mt][nt][r] = f2bs(vv);
            }
        }

    // direct row-major stores for q (sel0) and k (sel1)
    if (sel <= 1) {
        short* dst = (sel == 0) ? qraw : kbf;
        #pragma unroll
        for (int mt = 0; mt < 4; ++mt)
            #pragma unroll
            for (int r = 0; r < 4; ++r) {
                int t = t0 + wm + mt * 16 + quad * 4 + r;
                #pragma unroll
                for (int nt = 0; nt < 4; ++nt) {
                    int col = i0 + wn + nt * 16 + m16;
                    dst[((size_t)b * T_ + t) * E_ + col] = ov[mt][nt][r];
                }
            }
    }

    // transposed stores for k (sel1) and v (sel2) via LDS repack
    if (sel >= 1) {
        short* dstT = (sel == 1) ? kT : vT;
        #pragma unroll
        for (int h = 0; h < 2; ++h) {
            __syncthreads();                  // L free (gemm done / prev pass read)
            if (wm == 64 * h) {               // wave-uniform: waves owning this t-half
                #pragma unroll
                for (int mt = 0; mt < 4; ++mt)
                    #pragma unroll
                    for (int nt = 0; nt < 4; ++nt) {
                        int col = wn + nt * 16 + m16;      // 0..127
                        int tl = mt * 16 + quad * 4;       // 0..60
                        *(short4v*)&L[col * 68 + tl] = ov[mt][nt];
                    }
            }
            __syncthreads();
            #pragma unroll
            for (int rnd = 0; rnd < 4; ++rnd) {
                int col = rnd * 32 + (tid >> 3);           // 0..127
                int tt = (tid & 7) * 8;                    // 0..56
                short8 g = *(const short8*)&L[col * 68 + tt];
                *(short8*)(dstT + ((size_t)b * E_ + i0 + col) * T_ + t0 + 64 * h + tt) = g;
            }
        }
    }
}

// ---------------------------------------------------------------------------
// blocks [0,16384): softmax over q rows; blocks [16384,16512): per-chunk ksum
// ---------------------------------------------------------------------------
__global__ void softmax_ksum_kernel(const short* __restrict__ qraw, short* __restrict__ qbf,
                                    const short* __restrict__ k, float* __restrict__ ks) {
    int bid = blockIdx.x, tid = threadIdx.x;
    if (bid >= B_ * T_) {
        int r = bid - B_ * T_;             // 128 blocks: (bc=64, half=2)
        int bc = r >> 1, b = bc >> 3, c = bc & 7;
        int e = (r & 1) * 256 + tid;
        const short* kp = k + ((size_t)b * T_ + (size_t)c * CCH) * E_ + e;
        float s = 0.f;
        for (int t = 0; t < CCH; ++t) s += bs2f(kp[(size_t)t * E_]);
        ks[(size_t)bc * E_ + e] = s;
        return;
    }
    __shared__ float red[256];
    const short* p = qraw + (size_t)bid * E_;
    float v0 = bs2f(p[tid]), v1 = bs2f(p[tid + 256]);
    red[tid] = fmaxf(v0, v1);
    __syncthreads();
    for (int s = 128; s > 0; s >>= 1) { if (tid < s) red[tid] = fmaxf(red[tid], red[tid + s]); __syncthreads(); }
    float m = red[0];
    __syncthreads();
    float e0 = expf(v0 - m), e1 = expf(v1 - m);
    red[tid] = e0 + e1;
    __syncthreads();
    for (int s = 128; s > 0; s >>= 1) { if (tid < s) red[tid] += red[tid + s]; __syncthreads(); }
    float inv = QSCALE / red[0];
    qbf[(size_t)bid * E_ + tid] = f2bs(e0 * inv);
    qbf[(size_t)bid * E_ + tid + 256] = f2bs(e1 * inv);
}

// ---------------------------------------------------------------------------
// blocks [0,1024): chunk KV^T; blocks [1024,1280): intra-chunk P matrix
// ---------------------------------------------------------------------------
__global__ __launch_bounds__(256) void kvp_kernel(
    const short* __restrict__ vT, const short* __restrict__ kT, short* __restrict__ KV,
    const short* __restrict__ qbf, const short* __restrict__ kbf, short* __restrict__ P) {
    __shared__ __align__(16) short L[16384];
    int bid = blockIdx.x;
    if (bid < 1024) {
        GEMM_PROLOG
        int ev0 = (bid & 3) * 128, ek0 = ((bid >> 2) & 3) * 128;
        int bc = bid >> 4, b = bc >> 3, c = bc & 7;
        const short* Ag = vT + ((size_t)b * E_ + ev0) * T_ + c * CCH;
        const short* Bg = kT + ((size_t)b * E_ + ek0) * T_ + c * CCH;
        gemm128(Ag, T_, Bg, T_, CCH, L, acc, wm, wn, wq, lane);
        #pragma unroll
        for (int mt = 0; mt < 4; ++mt)
            #pragma unroll
            for (int r = 0; r < 4; ++r) {
                int ev = ev0 + wm + mt * 16 + quad * 4 + r;
                #pragma unroll
                for (int nt = 0; nt < 4; ++nt) {
                    int ek = ek0 + wn + nt * 16 + m16;
                    KV[((size_t)bc * E_ + ev) * E_ + ek] = f2bs(acc[mt][nt][r]);
                }
            }
        return;
    }
    bid -= 1024;
    int tj0 = (bid & 1) * 128, ti0 = ((bid >> 1) & 1) * 128;
    int bc = bid >> 2, b = bc >> 3, c = bc & 7;
    short* Pp = P + (size_t)bc * CCH * CCH;
    if (tj0 > ti0) {           // above diagonal: zero-fill (ws is poisoned)
        short8 z8 = {0, 0, 0, 0, 0, 0, 0, 0};
        for (int i = threadIdx.x; i < 128 * 128 / 8; i += 256) {
            int row = i >> 4, colc = (i * 8) & 127;
            *(short8*)(Pp + (size_t)(ti0 + row) * CCH + tj0 + colc) = z8;
        }
        return;
    }
    GEMM_PROLOG
    const short* Ag = qbf + ((size_t)b * T_ + c * CCH + ti0) * E_;
    const short* Bg = kbf + ((size_t)b * T_ + c * CCH + tj0) * E_;
    gemm128(Ag, E_, Bg, E_, E_, L, acc, wm, wn, wq, lane);
    #pragma unroll
    for (int mt = 0; mt < 4; ++mt)
        #pragma unroll
        for (int r = 0; r < 4; ++r) {
            int row = ti0 + wm + mt * 16 + quad * 4 + r;
            #pragma unroll
            for (int nt = 0; nt < 4; ++nt) {
                int col = tj0 + wn + nt * 16 + m16;
                float vv = (col <= row) ? acc[mt][nt][r] : 0.f;
                Pp[(size_t)row * CCH + col] = f2bs(vv);
            }
        }
}

// ---------------------------------------------------------------------------
// blocks [0,1024): exclusive chunk-scan of KV (bf16, 8 elem/thread);
// blocks [1024,1040): fp32 exclusive chunk-scan of ksum
// ---------------------------------------------------------------------------
__global__ void scan2_kernel(short* __restrict__ KV, float* __restrict__ ks) {
    int bid = blockIdx.x, tid = threadIdx.x;
    if (bid < 1024) {
        int gid = bid * 256 + tid;                 // B*E*E/8 = 262144 ids
        int b = gid >> 15;
        size_t idx = (size_t)(gid & 32767) * 8;
        short* p = KV + (size_t)b * NC_ * E_ * E_ + idx;
        float run[8] = {0.f, 0.f, 0.f, 0.f, 0.f, 0.f, 0.f, 0.f};
        #pragma unroll
        for (int c = 0; c < NC_; ++c) {
            short8 t8 = *(short8*)p;
            short8 o8;
            #pragma unroll
            for (int j = 0; j < 8; ++j) {
                float tv = bs2f(t8[j]);
                o8[j] = f2bs(run[j]);
                run[j] += tv;
            }
            *(short8*)p = o8;
            p += (size_t)E_ * E_;
        }
        return;
    }
    int gid = (bid - 1024) * 256 + tid;            // B*E = 4096 ids
    int b = gid >> 9, idx = gid & (E_ - 1);
    float run = 0.f;
    float* p = ks + (size_t)b * NC_ * E_ + idx;
    for (int c = 0; c < NC_; ++c) { float t = *p; *p = run; run += t; p += E_; }
}

// ---------------------------------------------------------------------------
__global__ void denom_kernel(const short* __restrict__ qbf, const float* __restrict__ z,
                             const short* __restrict__ P, float* __restrict__ invd) {
    __shared__ float red[256];
    int row = blockIdx.x, tid = threadIdx.x;
    int b = row >> 11, t = row & (T_ - 1);
    int c = t >> 8, tl = t & 255;
    const short* qr = qbf + (size_t)row * E_;
    const float* zr = z + ((size_t)(b * NC_ + c)) * E_;
    const short* Pr = P + (((size_t)(b * NC_ + c)) * CCH + tl) * CCH;
    float s = bs2f(qr[tid]) * zr[tid]
            + bs2f(qr[tid + 256]) * zr[tid + 256]
            + bs2f(Pr[tid]);
    red[tid] = s;
    __syncthreads();
    for (int st = 128; st > 0; st >>= 1) { if (tid < st) red[tid] += red[tid + st]; __syncthreads(); }
    if (tid == 0) invd[row] = 1.f / fmaxf(red[0], EPS_);
}

// ---------------------------------------------------------------------------
__global__ __launch_bounds__(256) void attnout_kernel(
    const short* __restrict__ qbf, const short* __restrict__ KV,
    const short* __restrict__ P, const short* __restrict__ vT,
    const float* __restrict__ invd, short* __restrict__ attn) {
    __shared__ __align__(16) short L[16384];
    GEMM_PROLOG
    int t0 = blockIdx.x * 128, i0 = blockIdx.y * 128, b = blockIdx.z;
    int c = t0 >> 8, tl0 = t0 & 255, bc = b * NC_ + c;
    gemm128(qbf + ((size_t)b * T_ + t0) * E_, E_,
            KV + ((size_t)bc * E_ + i0) * E_, E_, E_, L, acc, wm, wn, wq, lane);
    gemm128(P + ((size_t)bc * CCH + tl0) * CCH, CCH,
            vT + ((size_t)b * E_ + i0) * T_ + c * CCH, T_, CCH, L, acc, wm, wn, wq, lane);
    #pragma unroll
    for (int mt = 0; mt < 4; ++mt)
        #pragma unroll
        for (int r = 0; r < 4; ++r) {
            int t = t0 + wm + mt * 16 + quad * 4 + r;
            float sc = invd[(size_t)b * T_ + t];
            #pragma unroll
            for (int nt = 0; nt < 4; ++nt) {
                int col = i0 + wn + nt * 16 + m16;
                attn[((size_t)b * T_ + t) * E_ + col] = f2bs(acc[mt][nt][r] * sc);
            }
        }
}

// ---------------------------------------------------------------------------
__global__ __launch_bounds__(256) void outproj_kernel(
    const short* __restrict__ attn, const short* __restrict__ wbf_o,
    const float* __restrict__ ob, float* __restrict__ out) {
    __shared__ __align__(16) short L[16384];
    GEMM_PROLOG
    int t0 = blockIdx.x * 128, i0 = blockIdx.y * 128, b = blockIdx.z;
    gemm128(attn + ((size_t)b * T_ + t0) * E_, E_,
            wbf_o + (size_t)i0 * E_, E_, E_, L, acc, wm, wn, wq, lane);
    #pragma unroll
    for (int mt = 0; mt < 4; ++mt)
        #pragma unroll
        for (int r = 0; r < 4; ++r) {
            int t = t0 + wm + mt * 16 + quad * 4 + r;
            #pragma unroll
            for (int nt = 0; nt < 4; ++nt) {
                int col = i0 + wn + nt * 16 + m16;
                out[((size_t)b * T_ + t) * E_ + col] = acc[mt][nt][r] + ob[col];
            }
        }
}

// ---------------------------------------------------------------------------
extern "C" void kernel_launch(void* const* d_in, const int* in_sizes, int n_in,
                              void* d_out, int out_size, void* d_ws, size_t ws_size,
                              hipStream_t stream) {
    const float* x    = (const float*)d_in[0];
    const float* toep = (const float*)d_in[1];
    const float* q_w  = (const float*)d_in[2];
    const float* q_b  = (const float*)d_in[3];
    const float* k_w  = (const float*)d_in[4];
    const float* k_b  = (const float*)d_in[5];
    const float* v_w  = (const float*)d_in[6];
    const float* v_b  = (const float*)d_in[7];
    const float* o_w  = (const float*)d_in[8];
    const float* o_b  = (const float*)d_in[9];

    const size_t NTE = (size_t)B_ * T_ * E_;          // 8388608
    char* base = (char*)d_ws;
    short* xbf  = (short*)base;  base += NTE * 2;
    short* wbf  = (short*)base;  base += (size_t)4 * E_ * E_ * 2;
    short* qraw = (short*)base;  base += NTE * 2;
    short* qbf  = (short*)base;  base += NTE * 2;
    short* kbf  = (short*)base;  base += NTE * 2;
    short* kT   = (short*)base;  base += NTE * 2;
    short* vT   = (short*)base;  base += NTE * 2;
    short* KV   = (short*)base;  base += (size_t)B_ * NC_ * E_ * E_ * 2;
    short* P    = (short*)base;  base += (size_t)B_ * NC_ * CCH * CCH * 2;
    float* ksum = (float*)base;  base += (size_t)B_ * NC_ * E_ * 4;
    float* invd = (float*)base;  base += (size_t)B_ * T_ * 4;
    short* attn = xbf;           // xbf dead after proj_qkv: reuse for attn bf16
    float* out  = (float*)d_out;

    dim3 blk(256);
    prep_kernel<<<dim3(2560), blk, 0, stream>>>(q_w, k_w, v_w, o_w, wbf, x, xbf);
    proj_qkv_kernel<<<dim3(16, 4, 24), blk, 0, stream>>>(
        xbf, wbf, q_b, k_b, v_b, toep, qraw, kbf, kT, vT);
    softmax_ksum_kernel<<<dim3(B_ * T_ + 128), blk, 0, stream>>>(
        qraw, qbf, kbf, ksum);
    kvp_kernel<<<dim3(1280), blk, 0, stream>>>(
        vT, kT, KV, qbf, kbf, P);
    scan2_kernel<<<dim3(1040), blk, 0, stream>>>(KV, ksum);
    denom_kernel<<<dim3(B_ * T_), blk, 0, stream>>>(
        qbf, ksum, P, invd);
    attnout_kernel<<<dim3(16, 4, 8), blk, 0, stream>>>(
        qbf, KV, P, vT, invd, attn);
    outproj_kernel<<<dim3(16, 4, 8), blk, 0, stream>>>(
        attn, wbf + (size_t)3 * E_ * E_, o_b, out);
}